// Round 9
// baseline (254.438 us; speedup 1.0000x reference)
//
#include <hip/hip_runtime.h>

// RWKV6 TimeMix on MI355X — R14: revert gemm_proj to R12 (BK=64 double-buf,
// proven 53.4us; R13's 4-ring was -10% per unit work — cost is per-barrier,
// not load latency, and 2-phase 256^2 @K=1024 is AT its structural ceiling
// per m248v2). New: gemm_out off the 212TF 128^2 core onto the same 256^2
// BK=64 core via 4-way K-split (grid (16,4,4), K=256/slice, fp32 partials
// into dead workspace) + reduce_out. 256 blocks = 1/CU, no idle CUs.
//
//   K0 prep_w      : 5 weight matrices fp32 -> bf16
//   K1 prep_mix    : token-shift mix -> xr,xk,xv,xw (bf16)
//   K2 gemm_proj   : 4 projections (z-grid), 256^2/8-wave/BK64 MFMA
//   K3 scan_intra  : chunked (C=32) scan -> o_intra, rd, U_c, D_c
//   K4 state_prop  : S_{c+1} = D_c*S_c + U_c  (32 chunks)
//   K5 inter_ln    : O = o_intra + RD@S_c (MFMA), group-LN, *r -> oh (bf16)
//   K6 gemm_out_ks : 256^2/8-wave/BK64, 4-way K-split -> partials
//   K7 reduce_out  : sum 4 partials -> d_out
//
// Shapes: B=4, T=1024, D=1024, H=16, DH=64. Chunks: NC=32, C=32.

typedef unsigned short u16;
typedef unsigned int   u32;

typedef __attribute__((ext_vector_type(8))) __bf16 bf16x8;
typedef __attribute__((ext_vector_type(4))) float   f32x4;

#define MB (1u << 20)

#define LDS_PTR(p) ((__attribute__((address_space(3))) void*)(p))
#define GLB_PTR(p) ((const __attribute__((address_space(1))) void*)(p))

__device__ __forceinline__ u16 f2bf(float f) {
  u32 u = __builtin_bit_cast(u32, f);
  u += 0x7FFFu + ((u >> 16) & 1u);   // RNE; inputs are finite
  return (u16)(u >> 16);
}
__device__ __forceinline__ float bf2f(u16 x) {
  u32 u = ((u32)x) << 16;
  return __builtin_bit_cast(float, u);
}
__device__ __forceinline__ u32 pack2(float a, float b) {
  return (u32)f2bf(a) | ((u32)f2bf(b) << 16);
}

// ---------------- K0: weights fp32 -> bf16 (5 x 1M elements, 2-wide) --------
__global__ __launch_bounds__(256) void prep_w(
    const float* __restrict__ w0, const float* __restrict__ w1,
    const float* __restrict__ w2, const float* __restrict__ w3,
    const float* __restrict__ w4, u32* __restrict__ out) {
  int idx = blockIdx.x * 256 + threadIdx.x;   // pair index, 5*524288 total
  int m = idx >> 19;                          // matrix id (uniform per block)
  int l = idx & 524287;
  const float* src = (m == 0) ? w0 : (m == 1) ? w1 : (m == 2) ? w2 : (m == 3) ? w3 : w4;
  float2 v = *(const float2*)(src + (size_t)l * 2);
  out[idx] = pack2(v.x, v.y);
}

// ---------------- K1: token-shift mix -> bf16 (2-wide) ----------------------
__global__ __launch_bounds__(256) void prep_mix(
    const float* __restrict__ x,
    const float* __restrict__ tmr, const float* __restrict__ tmk,
    const float* __restrict__ tmv, const float* __restrict__ tmw,
    u32* __restrict__ xr, u32* __restrict__ xk,
    u32* __restrict__ xv, u32* __restrict__ xw) {
  int idx = blockIdx.x * 256 + threadIdx.x;   // pair index over 4*1024*512
  int t  = (idx >> 9) & 1023;
  int d0 = (idx & 511) * 2;
  size_t e = (size_t)idx * 2;
  float2 xc = *(const float2*)(x + e);
  float2 xp = make_float2(0.f, 0.f);
  if (t > 0) xp = *(const float2*)(x + e - 1024);
  float2 tm;
  tm = *(const float2*)(tmr + d0);
  xr[idx] = pack2(tm.x * xc.x + (1.f - tm.x) * xp.x, tm.y * xc.y + (1.f - tm.y) * xp.y);
  tm = *(const float2*)(tmk + d0);
  xk[idx] = pack2(tm.x * xc.x + (1.f - tm.x) * xp.x, tm.y * xc.y + (1.f - tm.y) * xp.y);
  tm = *(const float2*)(tmv + d0);
  xv[idx] = pack2(tm.x * xc.x + (1.f - tm.x) * xp.x, tm.y * xc.y + (1.f - tm.y) * xp.y);
  tm = *(const float2*)(tmw + d0);
  xw[idx] = pack2(tm.x * xc.x + (1.f - tm.x) * xp.x, tm.y * xc.y + (1.f - tm.y) * xp.y);
}

// ---------------- K2: 256x256xBK64 8-wave projection GEMM (R12 verbatim) ----
// C[m][n] = sum_k A[m][k]*W[n][k], M=4096, N=1024, K=1024, 4 mats via grid.z.
// 512 threads = 8 waves (2M x 4N); per-wave output 128x64 (M_rep=8, N_rep=4).
// Double-buffered global_load_lds, BK=64 (16 K-iters, 64 MFMA/wave/iter).
// LDS linear [256][64] u16; source chunk pre-swizzled (l&7)^(l>>3); reader
// chunk quad^(r16&7), kk=1 = ^32. vmcnt: steady 8, drain 0.
__global__ __launch_bounds__(512, 1) void gemm_proj(
    const u16* __restrict__ xr, const u16* __restrict__ xk,
    const u16* __restrict__ xv, const u16* __restrict__ xw,
    const u16* __restrict__ Wr, const u16* __restrict__ Wk,
    const u16* __restrict__ Wv, const u16* __restrict__ Ww,
    u16* __restrict__ rO, u16* __restrict__ kO,
    u16* __restrict__ vO, float* __restrict__ wO) {
  constexpr int KITER = 16;          // K = 1024 / 64
  constexpr int LDK   = 1024;        // u16 row stride of A and W
  __shared__ __align__(16) u16 Asm[2 * 16384];   // 2 x 32KB ([256][64] u16)
  __shared__ __align__(16) u16 Bsm[2 * 16384];   // 2 x 32KB

  int mat = blockIdx.z;              // uniform
  const u16* A = (mat == 0) ? xr : (mat == 1) ? xk : (mat == 2) ? xv : xw;
  const u16* W = (mat == 0) ? Wr : (mat == 1) ? Wk : (mat == 2) ? Wv : Ww;

  int tid = threadIdx.x;
  int m0 = blockIdx.x * 256, n0 = blockIdx.y * 256;
  int wave = tid >> 6, lane = tid & 63;
  int wm = (wave >> 2) * 128;        // {0,128}
  int wn = (wave & 3) * 64;          // {0,64,128,192}
  int r16 = lane & 15, quad = lane >> 4;

  f32x4 acc[8][4] = {};

  int lrow  = lane >> 3;             // 0..7
  int lchk  = (lane & 7) ^ lrow;     // swizzled source chunk
  const u16* Ag[4];
  const u16* Bg[4];
#pragma unroll
  for (int i = 0; i < 4; ++i) {
    int row = wave * 32 + i * 8 + lrow;
    Ag[i] = A + (size_t)(m0 + row) * LDK + lchk * 8;
    Bg[i] = W + (size_t)(n0 + row) * LDK + lchk * 8;
  }
  int ldsW = wave * 2048;            // u16 offset of this wave's 32-row stripe

  int aoff[8], boff[4];
#pragma unroll
  for (int mt = 0; mt < 8; ++mt) {
    int r = wm + mt * 16 + r16;
    aoff[mt] = r * 64 + (quad ^ (r16 & 7)) * 8;
  }
#pragma unroll
  for (int nt = 0; nt < 4; ++nt) {
    int r = wn + nt * 16 + r16;
    boff[nt] = r * 64 + (quad ^ (r16 & 7)) * 8;
  }

#define ISSUE_TILE(t, buf)                                                              \
  do {                                                                                  \
    int _o = (buf) * 16384 + ldsW, _k = (t) * 64;                                       \
    __builtin_amdgcn_global_load_lds(GLB_PTR(Ag[0] + _k), LDS_PTR(Asm + _o),        16, 0, 0); \
    __builtin_amdgcn_global_load_lds(GLB_PTR(Ag[1] + _k), LDS_PTR(Asm + _o + 512),  16, 0, 0); \
    __builtin_amdgcn_global_load_lds(GLB_PTR(Ag[2] + _k), LDS_PTR(Asm + _o + 1024), 16, 0, 0); \
    __builtin_amdgcn_global_load_lds(GLB_PTR(Ag[3] + _k), LDS_PTR(Asm + _o + 1536), 16, 0, 0); \
    __builtin_amdgcn_global_load_lds(GLB_PTR(Bg[0] + _k), LDS_PTR(Bsm + _o),        16, 0, 0); \
    __builtin_amdgcn_global_load_lds(GLB_PTR(Bg[1] + _k), LDS_PTR(Bsm + _o + 512),  16, 0, 0); \
    __builtin_amdgcn_global_load_lds(GLB_PTR(Bg[2] + _k), LDS_PTR(Bsm + _o + 1024), 16, 0, 0); \
    __builtin_amdgcn_global_load_lds(GLB_PTR(Bg[3] + _k), LDS_PTR(Bsm + _o + 1536), 16, 0, 0); \
  } while (0)

  ISSUE_TILE(0, 0);
  ISSUE_TILE(1, 1);                  // 16 loads outstanding

  int cur = 0;
  for (int i = 0; i < KITER; ++i) {
    if (i < KITER - 1) asm volatile("s_waitcnt vmcnt(8)" ::: "memory");
    else               asm volatile("s_waitcnt vmcnt(0)" ::: "memory");
    __builtin_amdgcn_s_barrier();    // all waves' tile-i data landed

    const u16* As = Asm + cur * 16384;
    const u16* Bs = Bsm + cur * 16384;
#pragma unroll
    for (int kk = 0; kk < 2; ++kk) {
      int kx = kk * 32;              // chunk ^4 == u16 offset ^32
      bf16x8 af[8], bfm[4];
#pragma unroll
      for (int mt = 0; mt < 8; ++mt) af[mt] = *(const bf16x8*)&As[aoff[mt] ^ kx];
#pragma unroll
      for (int nt = 0; nt < 4; ++nt) bfm[nt] = *(const bf16x8*)&Bs[boff[nt] ^ kx];
#pragma unroll
      for (int mt = 0; mt < 8; ++mt)
#pragma unroll
        for (int nt = 0; nt < 4; ++nt)
          acc[mt][nt] = __builtin_amdgcn_mfma_f32_16x16x32_bf16(af[mt], bfm[nt], acc[mt][nt], 0, 0, 0);
    }

    asm volatile("s_waitcnt lgkmcnt(0)" ::: "memory");  // my ds_reads done
    __builtin_amdgcn_s_barrier();                       // everyone's reads done
    if (i + 2 < KITER) ISSUE_TILE(i + 2, cur);          // re-target freed buffer
    cur ^= 1;
  }
#undef ISSUE_TILE

  // epilogue: C/D layout col=lane&15, row=quad*4+reg  [verified m89/m91]
#pragma unroll
  for (int mt = 0; mt < 8; ++mt) {
#pragma unroll
    for (int nt = 0; nt < 4; ++nt) {
#pragma unroll
      for (int rg = 0; rg < 4; ++rg) {
        int row = m0 + wm + mt * 16 + quad * 4 + rg;
        int col = n0 + wn + nt * 16 + r16;
        float v = acc[mt][nt][rg];
        size_t idx = (size_t)row * 1024 + col;
        if (mat == 0)      rO[idx] = f2bf(1.f / (1.f + __expf(-v)));
        else if (mat == 1) kO[idx] = f2bf(v);
        else if (mat == 2) vO[idx] = f2bf(v);
        else               wO[idx] = v;   // raw z; sigmoid folded into scan
      }
    }
  }
}

// ---------------- K6: output GEMM, 4-way K-split on the same 256^2 core -----
// M=4096, N=1024; grid (16,4,4): z = K-slice [z*256, z*256+256). KITER=4.
// Identical staging/swizzle/schedule to gemm_proj; fp32 partial per slice.
__global__ __launch_bounds__(512, 1) void gemm_out_ks(
    const u16* __restrict__ A0, const u16* __restrict__ W0,
    float* __restrict__ P0, float* __restrict__ P1,
    float* __restrict__ P2, float* __restrict__ P3) {
  constexpr int KITER = 4;           // K-slice = 256 / 64
  constexpr int LDK   = 1024;
  __shared__ __align__(16) u16 Asm[2 * 16384];
  __shared__ __align__(16) u16 Bsm[2 * 16384];

  int z = blockIdx.z;                // K-slice, uniform
  const u16* A = A0 + z * 256;
  const u16* W = W0 + z * 256;
  float* P = (z == 0) ? P0 : (z == 1) ? P1 : (z == 2) ? P2 : P3;

  int tid = threadIdx.x;
  int m0 = blockIdx.x * 256, n0 = blockIdx.y * 256;
  int wave = tid >> 6, lane = tid & 63;
  int wm = (wave >> 2) * 128;
  int wn = (wave & 3) * 64;
  int r16 = lane & 15, quad = lane >> 4;

  f32x4 acc[8][4] = {};

  int lrow  = lane >> 3;
  int lchk  = (lane & 7) ^ lrow;
  const u16* Ag[4];
  const u16* Bg[4];
#pragma unroll
  for (int i = 0; i < 4; ++i) {
    int row = wave * 32 + i * 8 + lrow;
    Ag[i] = A + (size_t)(m0 + row) * LDK + lchk * 8;
    Bg[i] = W + (size_t)(n0 + row) * LDK + lchk * 8;
  }
  int ldsW = wave * 2048;

  int aoff[8], boff[4];
#pragma unroll
  for (int mt = 0; mt < 8; ++mt) {
    int r = wm + mt * 16 + r16;
    aoff[mt] = r * 64 + (quad ^ (r16 & 7)) * 8;
  }
#pragma unroll
  for (int nt = 0; nt < 4; ++nt) {
    int r = wn + nt * 16 + r16;
    boff[nt] = r * 64 + (quad ^ (r16 & 7)) * 8;
  }

#define ISSUE_TILE(t, buf)                                                              \
  do {                                                                                  \
    int _o = (buf) * 16384 + ldsW, _k = (t) * 64;                                       \
    __builtin_amdgcn_global_load_lds(GLB_PTR(Ag[0] + _k), LDS_PTR(Asm + _o),        16, 0, 0); \
    __builtin_amdgcn_global_load_lds(GLB_PTR(Ag[1] + _k), LDS_PTR(Asm + _o + 512),  16, 0, 0); \
    __builtin_amdgcn_global_load_lds(GLB_PTR(Ag[2] + _k), LDS_PTR(Asm + _o + 1024), 16, 0, 0); \
    __builtin_amdgcn_global_load_lds(GLB_PTR(Ag[3] + _k), LDS_PTR(Asm + _o + 1536), 16, 0, 0); \
    __builtin_amdgcn_global_load_lds(GLB_PTR(Bg[0] + _k), LDS_PTR(Bsm + _o),        16, 0, 0); \
    __builtin_amdgcn_global_load_lds(GLB_PTR(Bg[1] + _k), LDS_PTR(Bsm + _o + 512),  16, 0, 0); \
    __builtin_amdgcn_global_load_lds(GLB_PTR(Bg[2] + _k), LDS_PTR(Bsm + _o + 1024), 16, 0, 0); \
    __builtin_amdgcn_global_load_lds(GLB_PTR(Bg[3] + _k), LDS_PTR(Bsm + _o + 1536), 16, 0, 0); \
  } while (0)

  ISSUE_TILE(0, 0);
  ISSUE_TILE(1, 1);

  int cur = 0;
  for (int i = 0; i < KITER; ++i) {
    if (i < KITER - 1) asm volatile("s_waitcnt vmcnt(8)" ::: "memory");
    else               asm volatile("s_waitcnt vmcnt(0)" ::: "memory");
    __builtin_amdgcn_s_barrier();

    const u16* As = Asm + cur * 16384;
    const u16* Bs = Bsm + cur * 16384;
#pragma unroll
    for (int kk = 0; kk < 2; ++kk) {
      int kx = kk * 32;
      bf16x8 af[8], bfm[4];
#pragma unroll
      for (int mt = 0; mt < 8; ++mt) af[mt] = *(const bf16x8*)&As[aoff[mt] ^ kx];
#pragma unroll
      for (int nt = 0; nt < 4; ++nt) bfm[nt] = *(const bf16x8*)&Bs[boff[nt] ^ kx];
#pragma unroll
      for (int mt = 0; mt < 8; ++mt)
#pragma unroll
        for (int nt = 0; nt < 4; ++nt)
          acc[mt][nt] = __builtin_amdgcn_mfma_f32_16x16x32_bf16(af[mt], bfm[nt], acc[mt][nt], 0, 0, 0);
    }

    asm volatile("s_waitcnt lgkmcnt(0)" ::: "memory");
    __builtin_amdgcn_s_barrier();
    if (i + 2 < KITER) ISSUE_TILE(i + 2, cur);
    cur ^= 1;
  }
#undef ISSUE_TILE

#pragma unroll
  for (int mt = 0; mt < 8; ++mt)
#pragma unroll
    for (int nt = 0; nt < 4; ++nt)
#pragma unroll
      for (int rg = 0; rg < 4; ++rg) {
        int row = m0 + wm + mt * 16 + quad * 4 + rg;
        int col = n0 + wn + nt * 16 + r16;
        P[(size_t)row * 1024 + col] = acc[mt][nt][rg];
      }
}

// ---------------- K7: reduce 4 partials -> out ------------------------------
__global__ __launch_bounds__(256) void reduce_out(
    const float4* __restrict__ p0, const float4* __restrict__ p1,
    const float4* __restrict__ p2, const float4* __restrict__ p3,
    float4* __restrict__ out) {
  int i = blockIdx.x * 256 + threadIdx.x;   // 1M float4
  float4 a = p0[i], b = p1[i], c = p2[i], d = p3[i];
  out[i] = make_float4(a.x + b.x + c.x + d.x, a.y + b.y + c.y + d.y,
                       a.z + b.z + c.z + d.z, a.w + b.w + c.w + d.w);
}

// ---------------- K3: intra-chunk scan, C=32, 16x16 thread map --------------
__global__ __launch_bounds__(256) void scan_intra(
    const u16* __restrict__ rb, const u16* __restrict__ kb,
    const u16* __restrict__ vb, const float* __restrict__ wb,
    const float* __restrict__ u,
    float* __restrict__ o, u16* __restrict__ rd,
    float* __restrict__ U, float* __restrict__ Dc) {
  int c = blockIdx.x, bh = blockIdx.y;
  int b = bh >> 4, h = bh & 15;
  int tid = threadIdx.x;
  int wave = tid >> 6, lane = tid & 63;
  int ig4 = tid >> 4, jq = tid & 15;

  __shared__ __align__(16) float4 combo[4][64];  // per-i: (r, k, exp(u+k), ew)
  __shared__ __align__(16) float4 vs4[4][16];    // v, viewed 4-wide
  __shared__ __align__(16) float  part[4][16][68];

  const float EW_SCALE = 0.99990001f;  // exp(-1e-4)

  float s[4][4];
#pragma unroll
  for (int ii = 0; ii < 4; ++ii)
#pragma unroll
    for (int jj = 0; jj < 4; ++jj) s[ii][jj] = 0.f;

  size_t base = ((size_t)(b * 1024 + c * 32)) * 1024 + h * 64 + lane;
  float dloc = 1.0f;
  float uval = (wave < 2) ? u[h * 64 + lane] : 0.f;   // combo stagers: i==lane

#define STAGE(t2, sl)                                                     \
  do {                                                                    \
    size_t _idx = base + (size_t)(t2) * 1024;                             \
    if (wave < 2) {                                                       \
      float _r = bf2f(rb[_idx]);                                          \
      float _k = bf2f(kb[_idx]);                                          \
      float _z = wb[_idx];                                                \
      combo[sl][lane] = make_float4(_r, _k, __expf(uval + _k),            \
                                    EW_SCALE / (1.f + __expf(-_z)));      \
    } else {                                                              \
      ((float*)vs4)[(sl) * 64 + lane] = bf2f(vb[_idx]);                   \
    }                                                                     \
  } while (0)

  // prologue: stage steps 0,1 (wave parity picks the step)
  { int p = wave & 1; STAGE(p, p); }
  __syncthreads();

  for (int tt = 0; tt < 32; tt += 2) {
    if (tt + 2 < 32) {
      int p = wave & 1;
      int t2 = tt + 2 + p;
      STAGE(t2, t2 & 3);
    }
    // compute steps tt, tt+1 (slots staged last interval, barrier crossed)
#pragma unroll
    for (int p = 0; p < 2; ++p) {
      int t = tt + p, sl = t & 3;
      float4 vv = vs4[sl][jq];
      float4 cb0 = combo[sl][ig4 * 4 + 0];
      float4 cb1 = combo[sl][ig4 * 4 + 1];
      float4 cb2 = combo[sl][ig4 * 4 + 2];
      float4 cb3 = combo[sl][ig4 * 4 + 3];
      float ac0 = 0.f, ac1 = 0.f, ac2 = 0.f, ac3 = 0.f;
#define ROW(cb, ii)                                                       \
      do {                                                                \
        float t0 = fmaf(cb.z, vv.x, s[ii][0]);                            \
        float t1 = fmaf(cb.z, vv.y, s[ii][1]);                            \
        float t2_ = fmaf(cb.z, vv.z, s[ii][2]);                           \
        float t3 = fmaf(cb.z, vv.w, s[ii][3]);                            \
        ac0 = fmaf(cb.x, t0, ac0);                                        \
        ac1 = fmaf(cb.x, t1, ac1);                                        \
        ac2 = fmaf(cb.x, t2_, ac2);                                       \
        ac3 = fmaf(cb.x, t3, ac3);                                        \
        s[ii][0] = fmaf(cb.w, s[ii][0], cb.y * vv.x);                     \
        s[ii][1] = fmaf(cb.w, s[ii][1], cb.y * vv.y);                     \
        s[ii][2] = fmaf(cb.w, s[ii][2], cb.y * vv.z);                     \
        s[ii][3] = fmaf(cb.w, s[ii][3], cb.y * vv.w);                     \
      } while (0)
      ROW(cb0, 0); ROW(cb1, 1); ROW(cb2, 2); ROW(cb3, 3);
#undef ROW
      *(float4*)&part[sl][ig4][jq * 4] = make_float4(ac0, ac1, ac2, ac3);
      if (wave == 0) {
        float4 me = combo[sl][lane];          // i == lane, vector b128
        rd[base + (size_t)t * 1024] = f2bf(me.x * dloc);
        dloc *= me.w;
      }
    }
    // store o for steps tt-2, tt-1 (parts complete since last barrier)
    if (tt >= 2) {
      if (wave == 2) {
        int t = tt - 2, sl = t & 3;
        float sum = 0.f;
#pragma unroll
        for (int g = 0; g < 16; ++g) sum += part[sl][g][lane];
        o[base + (size_t)t * 1024] = sum;
      } else if (wave == 3) {
        int t = tt - 1, sl = t & 3;
        float sum = 0.f;
#pragma unroll
        for (int g = 0; g < 16; ++g) sum += part[sl][g][lane];
        o[base + (size_t)t * 1024] = sum;
      }
    }
    __syncthreads();
  }
#undef STAGE
  // final two steps' o (slots 30&3=2, 31&3=3)
  if (wave == 2) {
    float sum = 0.f;
#pragma unroll
    for (int g = 0; g < 16; ++g) sum += part[2][g][lane];
    o[base + (size_t)30 * 1024] = sum;
  } else if (wave == 3) {
    float sum = 0.f;
#pragma unroll
    for (int g = 0; g < 16; ++g) sum += part[3][g][lane];
    o[base + (size_t)31 * 1024] = sum;
  }

  float* Ug = U + (size_t)(bh * 32 + c) * 4096;
#pragma unroll
  for (int ii = 0; ii < 4; ++ii) {
    *(float4*)&Ug[(ig4 * 4 + ii) * 64 + jq * 4] =
        make_float4(s[ii][0], s[ii][1], s[ii][2], s[ii][3]);
  }
  if (wave == 0) Dc[(bh * 32 + c) * 64 + lane] = dloc;
}

// ---------------- K4: chunk-state propagation (32 chunks) -------------------
__global__ __launch_bounds__(256) void state_prop(
    float* __restrict__ U, const float* __restrict__ Dc) {
  int bh  = blockIdx.x >> 4;
  int e   = (blockIdx.x & 15) * 256 + threadIdx.x;  // 0..4095
  int i   = e >> 6;
  float acc = 0.f;
  for (int c = 0; c < 32; ++c) {
    float* Ug = U + (size_t)(bh * 32 + c) * 4096 + e;
    float d = Dc[(bh * 32 + c) * 64 + i];
    float uv = *Ug;
    *Ug = acc;                      // write S_c (chunk-initial state)
    acc = fmaf(d, acc, uv);         // S_{c+1} = D_c*S_c + U_c
  }
}

// ---------------- K5: O = o_intra + RD@S_c (MFMA) + group-LN + gate --------
__global__ __launch_bounds__(128) void inter_ln(
    const float* __restrict__ o, const u16* __restrict__ rd,
    const u16* __restrict__ rb, const float* __restrict__ U,
    const float* __restrict__ lnw, const float* __restrict__ lnb,
    u16* __restrict__ oh) {
  int c = blockIdx.x, bh = blockIdx.y;
  int b = bh >> 4, h = bh & 15;
  int tid = threadIdx.x, wave = tid >> 6, lane = tid & 63;
  int l15 = lane & 15, quad = lane >> 4;

  __shared__ __align__(16) u16 Sb[64][72];   // Sb[j][i] = S_c[i][j] (bf16)

  const float* Sg = U + (size_t)(bh * 32 + c) * 4096;
#pragma unroll
  for (int q = 0; q < 32; ++q) {
    int e = q * 128 + tid;
    Sb[e & 63][e >> 6] = f2bf(Sg[e]);
  }
  __syncthreads();

  size_t rbase = ((size_t)(b * 1024 + c * 32)) * 1024 + h * 64;

  const u16* rdg = rd + rbase + (size_t)(wave * 16 + l15) * 1024 + quad * 8;
  bf16x8 af0 = *(const bf16x8*)(rdg);
  bf16x8 af1 = *(const bf16x8*)(rdg + 32);

  f32x4 acc[4] = {};
#pragma unroll
  for (int nt = 0; nt < 4; ++nt) {
    const u16* bp = &Sb[nt * 16 + l15][quad * 8];
    bf16x8 b0 = *(const bf16x8*)bp;
    bf16x8 b1 = *(const bf16x8*)(bp + 32);
    acc[nt] = __builtin_amdgcn_mfma_f32_16x16x32_bf16(af0, b0, acc[nt], 0, 0, 0);
    acc[nt] = __builtin_amdgcn_mfma_f32_16x16x32_bf16(af1, b1, acc[nt], 0, 0, 0);
  }

#pragma unroll
  for (int rg = 0; rg < 4; ++rg) {
    int t = wave * 16 + quad * 4 + rg;
    size_t rowb = rbase + (size_t)t * 1024;
    float v[4];
    float s1 = 0.f, s2 = 0.f;
#pragma unroll
    for (int nt = 0; nt < 4; ++nt) {
      v[nt] = acc[nt][rg] + o[rowb + nt * 16 + l15];
      s1 += v[nt];
      s2 += v[nt] * v[nt];
    }
#pragma unroll
    for (int m = 1; m < 16; m <<= 1) {   // reduce across the quad's 16 lanes
      s1 += __shfl_xor(s1, m, 64);
      s2 += __shfl_xor(s2, m, 64);
    }
    float mu  = s1 * (1.f / 64.f);
    float var = s2 * (1.f / 64.f) - mu * mu;
    float rstd = rsqrtf(var + 1e-5f);
#pragma unroll
    for (int nt = 0; nt < 4; ++nt) {
      int jj = nt * 16 + l15;
      float nv = (v[nt] - mu) * rstd;
      float val = (nv * lnw[jj] + lnb[jj]) * bf2f(rb[rowb + jj]);
      oh[rowb + jj] = f2bf(val);
    }
  }
}

// ---------------- launch -----------------------------------------------------
extern "C" void kernel_launch(void* const* d_in, const int* in_sizes, int n_in,
                              void* d_out, int out_size, void* d_ws, size_t ws_size,
                              hipStream_t stream) {
  const float* x    = (const float*)d_in[0];
  const float* W_r  = (const float*)d_in[1];
  const float* W_k  = (const float*)d_in[2];
  const float* W_v  = (const float*)d_in[3];
  const float* W_w  = (const float*)d_in[4];
  const float* W_o  = (const float*)d_in[5];
  const float* u    = (const float*)d_in[6];
  const float* tm_r = (const float*)d_in[7];
  const float* tm_k = (const float*)d_in[8];
  const float* tm_v = (const float*)d_in[9];
  const float* tm_w = (const float*)d_in[10];
  const float* ln_w = (const float*)d_in[11];
  const float* ln_b = (const float*)d_in[12];
  float* out = (float*)d_out;

  char* ws = (char*)d_ws;
  // region [0,32)MB: xr..xw during prep/gemm_proj; reused as Ubuf afterwards
  u16* xr = (u16*)(ws + (size_t)0 * MB);
  u16* xk = (u16*)(ws + (size_t)8 * MB);
  u16* xv = (u16*)(ws + (size_t)16 * MB);
  u16* xw = (u16*)(ws + (size_t)24 * MB);
  float* Ubuf = (float*)(ws + (size_t)0 * MB);   // 32MB (64bh x 32c x 4096)
  u16* Wb = (u16*)(ws + (size_t)32 * MB);   // 5 x 2MB: Wr,Wk,Wv,Ww,Wo
  u16* Wrb = Wb;
  u16* Wkb = (u16*)(ws + (size_t)34 * MB);
  u16* Wvb = (u16*)(ws + (size_t)36 * MB);
  u16* Wwb = (u16*)(ws + (size_t)38 * MB);
  u16* Wob = (u16*)(ws + (size_t)40 * MB);
  float* Dcbuf = (float*)(ws + (size_t)42 * MB); // 512KB (64bh x 32c x 64)
  u16*   rbuf = (u16*)(ws + (size_t)48 * MB);    // 8MB bf16
  u16*   kbuf = (u16*)(ws + (size_t)56 * MB);    // 8MB bf16
  u16*   vbuf = (u16*)(ws + (size_t)64 * MB);    // 8MB bf16
  float* wbuf = (float*)(ws + (size_t)72 * MB);  // 16MB fp32 (raw z for decay)
  float* obuf = (float*)(ws + (size_t)88 * MB);  // 16MB fp32 o_intra
  u16*  rdbuf = (u16*)(ws + (size_t)104 * MB);   // 8MB bf16
  u16*   ohbuf = (u16*)(ws + (size_t)129 * MB);  // 8MB
  // gemm_out partials: reuse [48,112)MB — rbuf/kbuf/vbuf/wbuf/obuf/rdbuf are
  // dead once inter_ln completes (stream-ordered before gemm_out_ks).
  float* P0 = (float*)(ws + (size_t)48 * MB);    // 16MB
  float* P1 = (float*)(ws + (size_t)64 * MB);    // 16MB
  float* P2 = (float*)(ws + (size_t)80 * MB);    // 16MB
  float* P3 = (float*)(ws + (size_t)96 * MB);    // 16MB

  prep_w<<<10240, 256, 0, stream>>>(W_r, W_k, W_v, W_w, W_o, (u32*)Wb);
  prep_mix<<<8192, 256, 0, stream>>>(x, tm_r, tm_k, tm_v, tm_w,
                                     (u32*)xr, (u32*)xk, (u32*)xv, (u32*)xw);
  gemm_proj<<<dim3(16, 4, 4), 512, 0, stream>>>(xr, xk, xv, xw,
                                                Wrb, Wkb, Wvb, Wwb,
                                                rbuf, kbuf, vbuf, wbuf);
  scan_intra<<<dim3(32, 64), 256, 0, stream>>>(rbuf, kbuf, vbuf, wbuf, u,
                                               obuf, rdbuf, Ubuf, Dcbuf);
  state_prop<<<1024, 256, 0, stream>>>(Ubuf, Dcbuf);
  inter_ln<<<dim3(32, 64), 128, 0, stream>>>(obuf, rdbuf, rbuf, Ubuf,
                                             ln_w, ln_b, ohbuf);
  gemm_out_ks<<<dim3(16, 4, 4), 512, 0, stream>>>(ohbuf, Wob, P0, P1, P2, P3);
  reduce_out<<<4096, 256, 0, stream>>>((const float4*)P0, (const float4*)P1,
                                       (const float4*)P2, (const float4*)P3,
                                       (float4*)out);
}

// Round 10
// 238.812 us; speedup vs baseline: 1.0654x; 1.0654x over previous
//
#include <hip/hip_runtime.h>

// RWKV6 TimeMix on MI355X — R15: split-K gemm_out through LDS (not HBM).
// R14's K-split via global partials added ~128MB traffic (+25us) for ~20us of
// compute saving -> net loss. R15: one 128x128-tile kernel, 8 waves = 2
// K-groups x 4; each group runs the VERIFIED BK=64 double-buffered pipeline
// on its K-half (identical staging/swizzle to gemm_proj); group 1 dumps acc
// to LDS (reusing dead staging buffers), one barrier, group 0 adds + stores.
// Zero extra HBM traffic, 2 waves/SIMD, half the serial K-chain.
//
//   K0 prep_w      : 5 weight matrices fp32 -> bf16
//   K1 prep_mix    : token-shift mix -> xr,xk,xv,xw (bf16)
//   K2 gemm_proj   : 4 projections (z-grid), 256^2/8-wave/BK64 MFMA
//   K3 scan_intra  : chunked (C=32) scan -> o_intra, rd, U_c, D_c
//   K4 state_prop  : S_{c+1} = D_c*S_c + U_c  (32 chunks)
//   K5 inter_ln    : O = o_intra + RD@S_c (MFMA), group-LN, *r -> oh (bf16)
//   K6 gemm_out_sk : 128^2 tile, 2 K-groups x 4 waves, LDS reduce -> d_out
//
// Shapes: B=4, T=1024, D=1024, H=16, DH=64. Chunks: NC=32, C=32.

typedef unsigned short u16;
typedef unsigned int   u32;

typedef __attribute__((ext_vector_type(8))) __bf16 bf16x8;
typedef __attribute__((ext_vector_type(4))) float   f32x4;

#define MB (1u << 20)

#define LDS_PTR(p) ((__attribute__((address_space(3))) void*)(p))
#define GLB_PTR(p) ((const __attribute__((address_space(1))) void*)(p))

__device__ __forceinline__ u16 f2bf(float f) {
  u32 u = __builtin_bit_cast(u32, f);
  u += 0x7FFFu + ((u >> 16) & 1u);   // RNE; inputs are finite
  return (u16)(u >> 16);
}
__device__ __forceinline__ float bf2f(u16 x) {
  u32 u = ((u32)x) << 16;
  return __builtin_bit_cast(float, u);
}
__device__ __forceinline__ u32 pack2(float a, float b) {
  return (u32)f2bf(a) | ((u32)f2bf(b) << 16);
}

// ---------------- K0: weights fp32 -> bf16 (5 x 1M elements, 2-wide) --------
__global__ __launch_bounds__(256) void prep_w(
    const float* __restrict__ w0, const float* __restrict__ w1,
    const float* __restrict__ w2, const float* __restrict__ w3,
    const float* __restrict__ w4, u32* __restrict__ out) {
  int idx = blockIdx.x * 256 + threadIdx.x;   // pair index, 5*524288 total
  int m = idx >> 19;                          // matrix id (uniform per block)
  int l = idx & 524287;
  const float* src = (m == 0) ? w0 : (m == 1) ? w1 : (m == 2) ? w2 : (m == 3) ? w3 : w4;
  float2 v = *(const float2*)(src + (size_t)l * 2);
  out[idx] = pack2(v.x, v.y);
}

// ---------------- K1: token-shift mix -> bf16 (2-wide) ----------------------
__global__ __launch_bounds__(256) void prep_mix(
    const float* __restrict__ x,
    const float* __restrict__ tmr, const float* __restrict__ tmk,
    const float* __restrict__ tmv, const float* __restrict__ tmw,
    u32* __restrict__ xr, u32* __restrict__ xk,
    u32* __restrict__ xv, u32* __restrict__ xw) {
  int idx = blockIdx.x * 256 + threadIdx.x;   // pair index over 4*1024*512
  int t  = (idx >> 9) & 1023;
  int d0 = (idx & 511) * 2;
  size_t e = (size_t)idx * 2;
  float2 xc = *(const float2*)(x + e);
  float2 xp = make_float2(0.f, 0.f);
  if (t > 0) xp = *(const float2*)(x + e - 1024);
  float2 tm;
  tm = *(const float2*)(tmr + d0);
  xr[idx] = pack2(tm.x * xc.x + (1.f - tm.x) * xp.x, tm.y * xc.y + (1.f - tm.y) * xp.y);
  tm = *(const float2*)(tmk + d0);
  xk[idx] = pack2(tm.x * xc.x + (1.f - tm.x) * xp.x, tm.y * xc.y + (1.f - tm.y) * xp.y);
  tm = *(const float2*)(tmv + d0);
  xv[idx] = pack2(tm.x * xc.x + (1.f - tm.x) * xp.x, tm.y * xc.y + (1.f - tm.y) * xp.y);
  tm = *(const float2*)(tmw + d0);
  xw[idx] = pack2(tm.x * xc.x + (1.f - tm.x) * xp.x, tm.y * xc.y + (1.f - tm.y) * xp.y);
}

// ---------------- K2: 256x256xBK64 8-wave projection GEMM (proven) ----------
__global__ __launch_bounds__(512, 1) void gemm_proj(
    const u16* __restrict__ xr, const u16* __restrict__ xk,
    const u16* __restrict__ xv, const u16* __restrict__ xw,
    const u16* __restrict__ Wr, const u16* __restrict__ Wk,
    const u16* __restrict__ Wv, const u16* __restrict__ Ww,
    u16* __restrict__ rO, u16* __restrict__ kO,
    u16* __restrict__ vO, float* __restrict__ wO) {
  constexpr int KITER = 16;          // K = 1024 / 64
  constexpr int LDK   = 1024;        // u16 row stride of A and W
  __shared__ __align__(16) u16 Asm[2 * 16384];   // 2 x 32KB ([256][64] u16)
  __shared__ __align__(16) u16 Bsm[2 * 16384];   // 2 x 32KB

  int mat = blockIdx.z;              // uniform
  const u16* A = (mat == 0) ? xr : (mat == 1) ? xk : (mat == 2) ? xv : xw;
  const u16* W = (mat == 0) ? Wr : (mat == 1) ? Wk : (mat == 2) ? Wv : Ww;

  int tid = threadIdx.x;
  int m0 = blockIdx.x * 256, n0 = blockIdx.y * 256;
  int wave = tid >> 6, lane = tid & 63;
  int wm = (wave >> 2) * 128;        // {0,128}
  int wn = (wave & 3) * 64;          // {0,64,128,192}
  int r16 = lane & 15, quad = lane >> 4;

  f32x4 acc[8][4] = {};

  int lrow  = lane >> 3;             // 0..7
  int lchk  = (lane & 7) ^ lrow;     // swizzled source chunk
  const u16* Ag[4];
  const u16* Bg[4];
#pragma unroll
  for (int i = 0; i < 4; ++i) {
    int row = wave * 32 + i * 8 + lrow;
    Ag[i] = A + (size_t)(m0 + row) * LDK + lchk * 8;
    Bg[i] = W + (size_t)(n0 + row) * LDK + lchk * 8;
  }
  int ldsW = wave * 2048;            // u16 offset of this wave's 32-row stripe

  int aoff[8], boff[4];
#pragma unroll
  for (int mt = 0; mt < 8; ++mt) {
    int r = wm + mt * 16 + r16;
    aoff[mt] = r * 64 + (quad ^ (r16 & 7)) * 8;
  }
#pragma unroll
  for (int nt = 0; nt < 4; ++nt) {
    int r = wn + nt * 16 + r16;
    boff[nt] = r * 64 + (quad ^ (r16 & 7)) * 8;
  }

#define ISSUE_TILE(t, buf)                                                              \
  do {                                                                                  \
    int _o = (buf) * 16384 + ldsW, _k = (t) * 64;                                       \
    __builtin_amdgcn_global_load_lds(GLB_PTR(Ag[0] + _k), LDS_PTR(Asm + _o),        16, 0, 0); \
    __builtin_amdgcn_global_load_lds(GLB_PTR(Ag[1] + _k), LDS_PTR(Asm + _o + 512),  16, 0, 0); \
    __builtin_amdgcn_global_load_lds(GLB_PTR(Ag[2] + _k), LDS_PTR(Asm + _o + 1024), 16, 0, 0); \
    __builtin_amdgcn_global_load_lds(GLB_PTR(Ag[3] + _k), LDS_PTR(Asm + _o + 1536), 16, 0, 0); \
    __builtin_amdgcn_global_load_lds(GLB_PTR(Bg[0] + _k), LDS_PTR(Bsm + _o),        16, 0, 0); \
    __builtin_amdgcn_global_load_lds(GLB_PTR(Bg[1] + _k), LDS_PTR(Bsm + _o + 512),  16, 0, 0); \
    __builtin_amdgcn_global_load_lds(GLB_PTR(Bg[2] + _k), LDS_PTR(Bsm + _o + 1024), 16, 0, 0); \
    __builtin_amdgcn_global_load_lds(GLB_PTR(Bg[3] + _k), LDS_PTR(Bsm + _o + 1536), 16, 0, 0); \
  } while (0)

  ISSUE_TILE(0, 0);
  ISSUE_TILE(1, 1);                  // 16 loads outstanding

  int cur = 0;
  for (int i = 0; i < KITER; ++i) {
    if (i < KITER - 1) asm volatile("s_waitcnt vmcnt(8)" ::: "memory");
    else               asm volatile("s_waitcnt vmcnt(0)" ::: "memory");
    __builtin_amdgcn_s_barrier();    // all waves' tile-i data landed

    const u16* As = Asm + cur * 16384;
    const u16* Bs = Bsm + cur * 16384;
#pragma unroll
    for (int kk = 0; kk < 2; ++kk) {
      int kx = kk * 32;              // chunk ^4 == u16 offset ^32
      bf16x8 af[8], bfm[4];
#pragma unroll
      for (int mt = 0; mt < 8; ++mt) af[mt] = *(const bf16x8*)&As[aoff[mt] ^ kx];
#pragma unroll
      for (int nt = 0; nt < 4; ++nt) bfm[nt] = *(const bf16x8*)&Bs[boff[nt] ^ kx];
#pragma unroll
      for (int mt = 0; mt < 8; ++mt)
#pragma unroll
        for (int nt = 0; nt < 4; ++nt)
          acc[mt][nt] = __builtin_amdgcn_mfma_f32_16x16x32_bf16(af[mt], bfm[nt], acc[mt][nt], 0, 0, 0);
    }

    asm volatile("s_waitcnt lgkmcnt(0)" ::: "memory");  // my ds_reads done
    __builtin_amdgcn_s_barrier();                       // everyone's reads done
    if (i + 2 < KITER) ISSUE_TILE(i + 2, cur);          // re-target freed buffer
    cur ^= 1;
  }
#undef ISSUE_TILE

  // epilogue: C/D layout col=lane&15, row=quad*4+reg  [verified m89/m91]
#pragma unroll
  for (int mt = 0; mt < 8; ++mt) {
#pragma unroll
    for (int nt = 0; nt < 4; ++nt) {
#pragma unroll
      for (int rg = 0; rg < 4; ++rg) {
        int row = m0 + wm + mt * 16 + quad * 4 + rg;
        int col = n0 + wn + nt * 16 + r16;
        float v = acc[mt][nt][rg];
        size_t idx = (size_t)row * 1024 + col;
        if (mat == 0)      rO[idx] = f2bf(1.f / (1.f + __expf(-v)));
        else if (mat == 1) kO[idx] = f2bf(v);
        else if (mat == 2) vO[idx] = f2bf(v);
        else               wO[idx] = v;   // raw z; sigmoid folded into scan
      }
    }
  }
}

// ---------------- K6: output GEMM, in-block split-K (LDS reduce) ------------
// M=4096, N=1024, K=1024. Tile 128x128; 512 thr = 2 K-groups x 4 waves.
// Group g: K in [g*512, g*512+512), BK=64, 8 iters, double-buffered — same
// staging/swizzle/read formulas as gemm_proj (wave -> w4, +g*512 k-offset).
// Epilogue: group 1 dumps acc (64 f32/thread) into the dead staging LDS,
// barrier, group 0 adds and stores. Grid (32,8) = 256 blocks = 1/CU.
__global__ __launch_bounds__(512, 1) void gemm_out_sk(
    const u16* __restrict__ A, const u16* __restrict__ W,
    float* __restrict__ O) {
  constexpr int KITER = 8;           // 512 / 64
  constexpr int LDK   = 1024;
  // [mat][grp][buf][128*64 u16] = 128KB; reused as f32 scratch for reduction.
  __shared__ __align__(16) u16 SMEM[2][2][2][8192];

  int tid = threadIdx.x;
  int m0 = blockIdx.x * 128, n0 = blockIdx.y * 128;
  int wave = tid >> 6, lane = tid & 63;
  int grp = wave >> 2, w4 = wave & 3;
  int wm = (w4 >> 1) * 64, wn = (w4 & 1) * 64;
  int r16 = lane & 15, quad = lane >> 4;

  f32x4 acc[4][4] = {};

  int lrow  = lane >> 3;             // 0..7
  int lchk  = (lane & 7) ^ lrow;     // swizzled source chunk
  const u16* Ag[4];
  const u16* Bg[4];
#pragma unroll
  for (int i = 0; i < 4; ++i) {
    int row = w4 * 32 + i * 8 + lrow;
    Ag[i] = A + (size_t)(m0 + row) * LDK + grp * 512 + lchk * 8;
    Bg[i] = W + (size_t)(n0 + row) * LDK + grp * 512 + lchk * 8;
  }
  u16* Abase = &SMEM[0][grp][0][0];
  u16* Bbase = &SMEM[1][grp][0][0];
  int ldsW = w4 * 2048;              // u16 offset of this wave's 32-row stripe

  int aoff[4], boff[4];
#pragma unroll
  for (int mt = 0; mt < 4; ++mt) {
    int r = wm + mt * 16 + r16;
    aoff[mt] = r * 64 + (quad ^ (r16 & 7)) * 8;
  }
#pragma unroll
  for (int nt = 0; nt < 4; ++nt) {
    int r = wn + nt * 16 + r16;
    boff[nt] = r * 64 + (quad ^ (r16 & 7)) * 8;
  }

#define ISSUE_TILE(t, buf)                                                              \
  do {                                                                                  \
    int _o = (buf) * 8192 + ldsW, _k = (t) * 64;                                        \
    __builtin_amdgcn_global_load_lds(GLB_PTR(Ag[0] + _k), LDS_PTR(Abase + _o),        16, 0, 0); \
    __builtin_amdgcn_global_load_lds(GLB_PTR(Ag[1] + _k), LDS_PTR(Abase + _o + 512),  16, 0, 0); \
    __builtin_amdgcn_global_load_lds(GLB_PTR(Ag[2] + _k), LDS_PTR(Abase + _o + 1024), 16, 0, 0); \
    __builtin_amdgcn_global_load_lds(GLB_PTR(Ag[3] + _k), LDS_PTR(Abase + _o + 1536), 16, 0, 0); \
    __builtin_amdgcn_global_load_lds(GLB_PTR(Bg[0] + _k), LDS_PTR(Bbase + _o),        16, 0, 0); \
    __builtin_amdgcn_global_load_lds(GLB_PTR(Bg[1] + _k), LDS_PTR(Bbase + _o + 512),  16, 0, 0); \
    __builtin_amdgcn_global_load_lds(GLB_PTR(Bg[2] + _k), LDS_PTR(Bbase + _o + 1024), 16, 0, 0); \
    __builtin_amdgcn_global_load_lds(GLB_PTR(Bg[3] + _k), LDS_PTR(Bbase + _o + 1536), 16, 0, 0); \
  } while (0)

  ISSUE_TILE(0, 0);
  ISSUE_TILE(1, 1);                  // 16 loads outstanding per wave

  int cur = 0;
  for (int i = 0; i < KITER; ++i) {
    if (i < KITER - 1) asm volatile("s_waitcnt vmcnt(8)" ::: "memory");
    else               asm volatile("s_waitcnt vmcnt(0)" ::: "memory");
    __builtin_amdgcn_s_barrier();    // all waves' tile-i data landed

    const u16* As = Abase + cur * 8192;
    const u16* Bs = Bbase + cur * 8192;
#pragma unroll
    for (int kk = 0; kk < 2; ++kk) {
      int kx = kk * 32;
      bf16x8 af[4], bfm[4];
#pragma unroll
      for (int mt = 0; mt < 4; ++mt) af[mt] = *(const bf16x8*)&As[aoff[mt] ^ kx];
#pragma unroll
      for (int nt = 0; nt < 4; ++nt) bfm[nt] = *(const bf16x8*)&Bs[boff[nt] ^ kx];
#pragma unroll
      for (int mt = 0; mt < 4; ++mt)
#pragma unroll
        for (int nt = 0; nt < 4; ++nt)
          acc[mt][nt] = __builtin_amdgcn_mfma_f32_16x16x32_bf16(af[mt], bfm[nt], acc[mt][nt], 0, 0, 0);
    }

    asm volatile("s_waitcnt lgkmcnt(0)" ::: "memory");
    __builtin_amdgcn_s_barrier();
    if (i + 2 < KITER) ISSUE_TILE(i + 2, cur);
    cur ^= 1;
  }
#undef ISSUE_TILE

  // split-K reduction through LDS (staging buffers are dead now).
  float* red = (float*)&SMEM[0][0][0][0];   // 32768 floats available
  int slot = (tid & 255) * 68;              // 68-pad breaks bank alignment
  if (grp == 1) {
#pragma unroll
    for (int mt = 0; mt < 4; ++mt)
#pragma unroll
      for (int nt = 0; nt < 4; ++nt)
        *(f32x4*)&red[slot + (mt * 4 + nt) * 4] = acc[mt][nt];
  }
  __syncthreads();
  if (grp == 0) {
#pragma unroll
    for (int mt = 0; mt < 4; ++mt) {
#pragma unroll
      for (int nt = 0; nt < 4; ++nt) {
        f32x4 other = *(const f32x4*)&red[slot + (mt * 4 + nt) * 4];
#pragma unroll
        for (int rg = 0; rg < 4; ++rg) {
          int row = m0 + wm + mt * 16 + quad * 4 + rg;
          int col = n0 + wn + nt * 16 + r16;
          O[(size_t)row * 1024 + col] = acc[mt][nt][rg] + other[rg];
        }
      }
    }
  }
}

// ---------------- K3: intra-chunk scan, C=32, 16x16 thread map --------------
__global__ __launch_bounds__(256) void scan_intra(
    const u16* __restrict__ rb, const u16* __restrict__ kb,
    const u16* __restrict__ vb, const float* __restrict__ wb,
    const float* __restrict__ u,
    float* __restrict__ o, u16* __restrict__ rd,
    float* __restrict__ U, float* __restrict__ Dc) {
  int c = blockIdx.x, bh = blockIdx.y;
  int b = bh >> 4, h = bh & 15;
  int tid = threadIdx.x;
  int wave = tid >> 6, lane = tid & 63;
  int ig4 = tid >> 4, jq = tid & 15;

  __shared__ __align__(16) float4 combo[4][64];  // per-i: (r, k, exp(u+k), ew)
  __shared__ __align__(16) float4 vs4[4][16];    // v, viewed 4-wide
  __shared__ __align__(16) float  part[4][16][68];

  const float EW_SCALE = 0.99990001f;  // exp(-1e-4)

  float s[4][4];
#pragma unroll
  for (int ii = 0; ii < 4; ++ii)
#pragma unroll
    for (int jj = 0; jj < 4; ++jj) s[ii][jj] = 0.f;

  size_t base = ((size_t)(b * 1024 + c * 32)) * 1024 + h * 64 + lane;
  float dloc = 1.0f;
  float uval = (wave < 2) ? u[h * 64 + lane] : 0.f;   // combo stagers: i==lane

#define STAGE(t2, sl)                                                     \
  do {                                                                    \
    size_t _idx = base + (size_t)(t2) * 1024;                             \
    if (wave < 2) {                                                       \
      float _r = bf2f(rb[_idx]);                                          \
      float _k = bf2f(kb[_idx]);                                          \
      float _z = wb[_idx];                                                \
      combo[sl][lane] = make_float4(_r, _k, __expf(uval + _k),            \
                                    EW_SCALE / (1.f + __expf(-_z)));      \
    } else {                                                              \
      ((float*)vs4)[(sl) * 64 + lane] = bf2f(vb[_idx]);                   \
    }                                                                     \
  } while (0)

  // prologue: stage steps 0,1 (wave parity picks the step)
  { int p = wave & 1; STAGE(p, p); }
  __syncthreads();

  for (int tt = 0; tt < 32; tt += 2) {
    if (tt + 2 < 32) {
      int p = wave & 1;
      int t2 = tt + 2 + p;
      STAGE(t2, t2 & 3);
    }
    // compute steps tt, tt+1 (slots staged last interval, barrier crossed)
#pragma unroll
    for (int p = 0; p < 2; ++p) {
      int t = tt + p, sl = t & 3;
      float4 vv = vs4[sl][jq];
      float4 cb0 = combo[sl][ig4 * 4 + 0];
      float4 cb1 = combo[sl][ig4 * 4 + 1];
      float4 cb2 = combo[sl][ig4 * 4 + 2];
      float4 cb3 = combo[sl][ig4 * 4 + 3];
      float ac0 = 0.f, ac1 = 0.f, ac2 = 0.f, ac3 = 0.f;
#define ROW(cb, ii)                                                       \
      do {                                                                \
        float t0 = fmaf(cb.z, vv.x, s[ii][0]);                            \
        float t1 = fmaf(cb.z, vv.y, s[ii][1]);                            \
        float t2_ = fmaf(cb.z, vv.z, s[ii][2]);                           \
        float t3 = fmaf(cb.z, vv.w, s[ii][3]);                            \
        ac0 = fmaf(cb.x, t0, ac0);                                        \
        ac1 = fmaf(cb.x, t1, ac1);                                        \
        ac2 = fmaf(cb.x, t2_, ac2);                                       \
        ac3 = fmaf(cb.x, t3, ac3);                                        \
        s[ii][0] = fmaf(cb.w, s[ii][0], cb.y * vv.x);                     \
        s[ii][1] = fmaf(cb.w, s[ii][1], cb.y * vv.y);                     \
        s[ii][2] = fmaf(cb.w, s[ii][2], cb.y * vv.z);                     \
        s[ii][3] = fmaf(cb.w, s[ii][3], cb.y * vv.w);                     \
      } while (0)
      ROW(cb0, 0); ROW(cb1, 1); ROW(cb2, 2); ROW(cb3, 3);
#undef ROW
      *(float4*)&part[sl][ig4][jq * 4] = make_float4(ac0, ac1, ac2, ac3);
      if (wave == 0) {
        float4 me = combo[sl][lane];          // i == lane, vector b128
        rd[base + (size_t)t * 1024] = f2bf(me.x * dloc);
        dloc *= me.w;
      }
    }
    // store o for steps tt-2, tt-1 (parts complete since last barrier)
    if (tt >= 2) {
      if (wave == 2) {
        int t = tt - 2, sl = t & 3;
        float sum = 0.f;
#pragma unroll
        for (int g = 0; g < 16; ++g) sum += part[sl][g][lane];
        o[base + (size_t)t * 1024] = sum;
      } else if (wave == 3) {
        int t = tt - 1, sl = t & 3;
        float sum = 0.f;
#pragma unroll
        for (int g = 0; g < 16; ++g) sum += part[sl][g][lane];
        o[base + (size_t)t * 1024] = sum;
      }
    }
    __syncthreads();
  }
#undef STAGE
  // final two steps' o (slots 30&3=2, 31&3=3)
  if (wave == 2) {
    float sum = 0.f;
#pragma unroll
    for (int g = 0; g < 16; ++g) sum += part[2][g][lane];
    o[base + (size_t)30 * 1024] = sum;
  } else if (wave == 3) {
    float sum = 0.f;
#pragma unroll
    for (int g = 0; g < 16; ++g) sum += part[3][g][lane];
    o[base + (size_t)31 * 1024] = sum;
  }

  float* Ug = U + (size_t)(bh * 32 + c) * 4096;
#pragma unroll
  for (int ii = 0; ii < 4; ++ii) {
    *(float4*)&Ug[(ig4 * 4 + ii) * 64 + jq * 4] =
        make_float4(s[ii][0], s[ii][1], s[ii][2], s[ii][3]);
  }
  if (wave == 0) Dc[(bh * 32 + c) * 64 + lane] = dloc;
}

// ---------------- K4: chunk-state propagation (32 chunks) -------------------
__global__ __launch_bounds__(256) void state_prop(
    float* __restrict__ U, const float* __restrict__ Dc) {
  int bh  = blockIdx.x >> 4;
  int e   = (blockIdx.x & 15) * 256 + threadIdx.x;  // 0..4095
  int i   = e >> 6;
  float acc = 0.f;
  for (int c = 0; c < 32; ++c) {
    float* Ug = U + (size_t)(bh * 32 + c) * 4096 + e;
    float d = Dc[(bh * 32 + c) * 64 + i];
    float uv = *Ug;
    *Ug = acc;                      // write S_c (chunk-initial state)
    acc = fmaf(d, acc, uv);         // S_{c+1} = D_c*S_c + U_c
  }
}

// ---------------- K5: O = o_intra + RD@S_c (MFMA) + group-LN + gate --------
__global__ __launch_bounds__(128) void inter_ln(
    const float* __restrict__ o, const u16* __restrict__ rd,
    const u16* __restrict__ rb, const float* __restrict__ U,
    const float* __restrict__ lnw, const float* __restrict__ lnb,
    u16* __restrict__ oh) {
  int c = blockIdx.x, bh = blockIdx.y;
  int b = bh >> 4, h = bh & 15;
  int tid = threadIdx.x, wave = tid >> 6, lane = tid & 63;
  int l15 = lane & 15, quad = lane >> 4;

  __shared__ __align__(16) u16 Sb[64][72];   // Sb[j][i] = S_c[i][j] (bf16)

  const float* Sg = U + (size_t)(bh * 32 + c) * 4096;
#pragma unroll
  for (int q = 0; q < 32; ++q) {
    int e = q * 128 + tid;
    Sb[e & 63][e >> 6] = f2bf(Sg[e]);
  }
  __syncthreads();

  size_t rbase = ((size_t)(b * 1024 + c * 32)) * 1024 + h * 64;

  const u16* rdg = rd + rbase + (size_t)(wave * 16 + l15) * 1024 + quad * 8;
  bf16x8 af0 = *(const bf16x8*)(rdg);
  bf16x8 af1 = *(const bf16x8*)(rdg + 32);

  f32x4 acc[4] = {};
#pragma unroll
  for (int nt = 0; nt < 4; ++nt) {
    const u16* bp = &Sb[nt * 16 + l15][quad * 8];
    bf16x8 b0 = *(const bf16x8*)bp;
    bf16x8 b1 = *(const bf16x8*)(bp + 32);
    acc[nt] = __builtin_amdgcn_mfma_f32_16x16x32_bf16(af0, b0, acc[nt], 0, 0, 0);
    acc[nt] = __builtin_amdgcn_mfma_f32_16x16x32_bf16(af1, b1, acc[nt], 0, 0, 0);
  }

#pragma unroll
  for (int rg = 0; rg < 4; ++rg) {
    int t = wave * 16 + quad * 4 + rg;
    size_t rowb = rbase + (size_t)t * 1024;
    float v[4];
    float s1 = 0.f, s2 = 0.f;
#pragma unroll
    for (int nt = 0; nt < 4; ++nt) {
      v[nt] = acc[nt][rg] + o[rowb + nt * 16 + l15];
      s1 += v[nt];
      s2 += v[nt] * v[nt];
    }
#pragma unroll
    for (int m = 1; m < 16; m <<= 1) {   // reduce across the quad's 16 lanes
      s1 += __shfl_xor(s1, m, 64);
      s2 += __shfl_xor(s2, m, 64);
    }
    float mu  = s1 * (1.f / 64.f);
    float var = s2 * (1.f / 64.f) - mu * mu;
    float rstd = rsqrtf(var + 1e-5f);
#pragma unroll
    for (int nt = 0; nt < 4; ++nt) {
      int jj = nt * 16 + l15;
      float nv = (v[nt] - mu) * rstd;
      float val = (nv * lnw[jj] + lnb[jj]) * bf2f(rb[rowb + jj]);
      oh[rowb + jj] = f2bf(val);
    }
  }
}

// ---------------- launch -----------------------------------------------------
extern "C" void kernel_launch(void* const* d_in, const int* in_sizes, int n_in,
                              void* d_out, int out_size, void* d_ws, size_t ws_size,
                              hipStream_t stream) {
  const float* x    = (const float*)d_in[0];
  const float* W_r  = (const float*)d_in[1];
  const float* W_k  = (const float*)d_in[2];
  const float* W_v  = (const float*)d_in[3];
  const float* W_w  = (const float*)d_in[4];
  const float* W_o  = (const float*)d_in[5];
  const float* u    = (const float*)d_in[6];
  const float* tm_r = (const float*)d_in[7];
  const float* tm_k = (const float*)d_in[8];
  const float* tm_v = (const float*)d_in[9];
  const float* tm_w = (const float*)d_in[10];
  const float* ln_w = (const float*)d_in[11];
  const float* ln_b = (const float*)d_in[12];
  float* out = (float*)d_out;

  char* ws = (char*)d_ws;
  // region [0,32)MB: xr..xw during prep/gemm_proj; reused as Ubuf afterwards
  u16* xr = (u16*)(ws + (size_t)0 * MB);
  u16* xk = (u16*)(ws + (size_t)8 * MB);
  u16* xv = (u16*)(ws + (size_t)16 * MB);
  u16* xw = (u16*)(ws + (size_t)24 * MB);
  float* Ubuf = (float*)(ws + (size_t)0 * MB);   // 32MB (64bh x 32c x 4096)
  u16* Wb = (u16*)(ws + (size_t)32 * MB);   // 5 x 2MB: Wr,Wk,Wv,Ww,Wo
  u16* Wrb = Wb;
  u16* Wkb = (u16*)(ws + (size_t)34 * MB);
  u16* Wvb = (u16*)(ws + (size_t)36 * MB);
  u16* Wwb = (u16*)(ws + (size_t)38 * MB);
  u16* Wob = (u16*)(ws + (size_t)40 * MB);
  float* Dcbuf = (float*)(ws + (size_t)42 * MB); // 512KB (64bh x 32c x 64)
  u16*   rbuf = (u16*)(ws + (size_t)48 * MB);    // 8MB bf16
  u16*   kbuf = (u16*)(ws + (size_t)56 * MB);    // 8MB bf16
  u16*   vbuf = (u16*)(ws + (size_t)64 * MB);    // 8MB bf16
  float* wbuf = (float*)(ws + (size_t)72 * MB);  // 16MB fp32 (raw z for decay)
  float* obuf = (float*)(ws + (size_t)88 * MB);  // 16MB fp32 o_intra
  u16*  rdbuf = (u16*)(ws + (size_t)104 * MB);   // 8MB bf16
  u16*   ohbuf = (u16*)(ws + (size_t)129 * MB);  // 8MB

  prep_w<<<10240, 256, 0, stream>>>(W_r, W_k, W_v, W_w, W_o, (u32*)Wb);
  prep_mix<<<8192, 256, 0, stream>>>(x, tm_r, tm_k, tm_v, tm_w,
                                     (u32*)xr, (u32*)xk, (u32*)xv, (u32*)xw);
  gemm_proj<<<dim3(16, 4, 4), 512, 0, stream>>>(xr, xk, xv, xw,
                                                Wrb, Wkb, Wvb, Wwb,
                                                rbuf, kbuf, vbuf, wbuf);
  scan_intra<<<dim3(32, 64), 256, 0, stream>>>(rbuf, kbuf, vbuf, wbuf, u,
                                               obuf, rdbuf, Ubuf, Dcbuf);
  state_prop<<<1024, 256, 0, stream>>>(Ubuf, Dcbuf);
  inter_ln<<<dim3(32, 64), 128, 0, stream>>>(obuf, rdbuf, rbuf, Ubuf,
                                             ln_w, ln_b, ohbuf);
  gemm_out_sk<<<dim3(32, 8), 512, 0, stream>>>(ohbuf, Wob, out);
}

// Round 11
// 232.849 us; speedup vs baseline: 1.0927x; 1.0256x over previous
//
#include <hip/hip_runtime.h>

// RWKV6 TimeMix on MI355X — R16: traffic + locality consolidation.
// R15 landed (238.8us); gemm_proj at 665 TF = the 2-phase 256^2 structural
// ceiling (m248v2: 666). This round: (1) S_c stored bf16 at state_prop
// (inter_ln already casts S->bf16 for MFMA, so this is bit-identical math;
// kills 32MB fp32 U-writeback + halves inter_ln's S read = -48MB HBM);
// (2) bijective XCD-swizzle on both GEMMs (panel-sharing blocks -> same XCD,
// FETCH 49.5->~42MB); (3) prep_w+prep_mix merged (one less launch gap).
//
//   K0 prep_all    : weights fp32->bf16 + token-shift mix (merged)
//   K1 gemm_proj   : 4 projections, 256^2/8-wave/BK64, XCD-swizzled
//   K2 scan_intra  : chunked (C=32) scan -> o_intra, rd, U_c, D_c
//   K3 state_prop  : S_{c+1} = D_c*S_c + U_c; writes S_c as bf16
//   K4 inter_ln    : O = o_intra + RD@S_c (MFMA), group-LN, *r -> oh (bf16)
//   K5 gemm_out_sk : 128^2 tile, 2 K-groups x 4 waves, LDS reduce, swizzled
//
// Shapes: B=4, T=1024, D=1024, H=16, DH=64. Chunks: NC=32, C=32.

typedef unsigned short u16;
typedef unsigned int   u32;

typedef __attribute__((ext_vector_type(8))) __bf16 bf16x8;
typedef __attribute__((ext_vector_type(4))) float   f32x4;

#define MB (1u << 20)

#define LDS_PTR(p) ((__attribute__((address_space(3))) void*)(p))
#define GLB_PTR(p) ((const __attribute__((address_space(1))) void*)(p))

__device__ __forceinline__ u16 f2bf(float f) {
  u32 u = __builtin_bit_cast(u32, f);
  u += 0x7FFFu + ((u >> 16) & 1u);   // RNE; inputs are finite
  return (u16)(u >> 16);
}
__device__ __forceinline__ float bf2f(u16 x) {
  u32 u = ((u32)x) << 16;
  return __builtin_bit_cast(float, u);
}
__device__ __forceinline__ u32 pack2(float a, float b) {
  return (u32)f2bf(a) | ((u32)f2bf(b) << 16);
}

// ---------------- K0: merged weight-cast + token-shift mix ------------------
__global__ __launch_bounds__(256) void prep_all(
    const float* __restrict__ w0, const float* __restrict__ w1,
    const float* __restrict__ w2, const float* __restrict__ w3,
    const float* __restrict__ w4, u32* __restrict__ wout,
    const float* __restrict__ x,
    const float* __restrict__ tmr, const float* __restrict__ tmk,
    const float* __restrict__ tmv, const float* __restrict__ tmw,
    u32* __restrict__ xr, u32* __restrict__ xk,
    u32* __restrict__ xv, u32* __restrict__ xw) {
  int bid = blockIdx.x;
  if (bid < 10240) {                          // weight cast: 5 x 524288 pairs
    int idx = bid * 256 + threadIdx.x;
    int m = idx >> 19;
    int l = idx & 524287;
    const float* src = (m == 0) ? w0 : (m == 1) ? w1 : (m == 2) ? w2 : (m == 3) ? w3 : w4;
    float2 v = *(const float2*)(src + (size_t)l * 2);
    wout[idx] = pack2(v.x, v.y);
  } else {                                    // token-shift mix
    int idx = (bid - 10240) * 256 + threadIdx.x;  // pair index over 4*1024*512
    int t  = (idx >> 9) & 1023;
    int d0 = (idx & 511) * 2;
    size_t e = (size_t)idx * 2;
    float2 xc = *(const float2*)(x + e);
    float2 xp = make_float2(0.f, 0.f);
    if (t > 0) xp = *(const float2*)(x + e - 1024);
    float2 tm;
    tm = *(const float2*)(tmr + d0);
    xr[idx] = pack2(tm.x * xc.x + (1.f - tm.x) * xp.x, tm.y * xc.y + (1.f - tm.y) * xp.y);
    tm = *(const float2*)(tmk + d0);
    xk[idx] = pack2(tm.x * xc.x + (1.f - tm.x) * xp.x, tm.y * xc.y + (1.f - tm.y) * xp.y);
    tm = *(const float2*)(tmv + d0);
    xv[idx] = pack2(tm.x * xc.x + (1.f - tm.x) * xp.x, tm.y * xc.y + (1.f - tm.y) * xp.y);
    tm = *(const float2*)(tmw + d0);
    xw[idx] = pack2(tm.x * xc.x + (1.f - tm.x) * xp.x, tm.y * xc.y + (1.f - tm.y) * xp.y);
  }
}

// ---------------- K1: 256x256xBK64 8-wave projection GEMM (proven core) -----
// 1-D grid 256, bijective XCD decode: d&7 = XCD; groups g=(y+4*mat) with the
// same W-panel land on one XCD (XCD k gets groups {k, k+8}).
__global__ __launch_bounds__(512, 1) void gemm_proj(
    const u16* __restrict__ xr, const u16* __restrict__ xk,
    const u16* __restrict__ xv, const u16* __restrict__ xw,
    const u16* __restrict__ Wr, const u16* __restrict__ Wk,
    const u16* __restrict__ Wv, const u16* __restrict__ Ww,
    u16* __restrict__ rO, u16* __restrict__ kO,
    u16* __restrict__ vO, float* __restrict__ wO) {
  constexpr int KITER = 16;          // K = 1024 / 64
  constexpr int LDK   = 1024;        // u16 row stride of A and W
  __shared__ __align__(16) u16 Asm[2 * 16384];   // 2 x 32KB ([256][64] u16)
  __shared__ __align__(16) u16 Bsm[2 * 16384];   // 2 x 32KB

  // XCD-aware decode (assumes dispatch round-robins blockIdx over 8 XCDs)
  int d  = blockIdx.x;               // 0..255
  int k8 = d & 7, q = d >> 3;        // q in [0,32)
  int gh = q >> 4;                   // 0..1
  int xt = q & 15;                   // m-tile 0..15
  int g  = k8 + 8 * gh;              // group = y + 4*mat
  int yt = g & 3, mat = g >> 2;      // n-tile, matrix id (uniform)

  const u16* A = (mat == 0) ? xr : (mat == 1) ? xk : (mat == 2) ? xv : xw;
  const u16* W = (mat == 0) ? Wr : (mat == 1) ? Wk : (mat == 2) ? Wv : Ww;

  int tid = threadIdx.x;
  int m0 = xt * 256, n0 = yt * 256;
  int wave = tid >> 6, lane = tid & 63;
  int wm = (wave >> 2) * 128;        // {0,128}
  int wn = (wave & 3) * 64;          // {0,64,128,192}
  int r16 = lane & 15, quad = lane >> 4;

  f32x4 acc[8][4] = {};

  int lrow  = lane >> 3;             // 0..7
  int lchk  = (lane & 7) ^ lrow;     // swizzled source chunk
  const u16* Ag[4];
  const u16* Bg[4];
#pragma unroll
  for (int i = 0; i < 4; ++i) {
    int row = wave * 32 + i * 8 + lrow;
    Ag[i] = A + (size_t)(m0 + row) * LDK + lchk * 8;
    Bg[i] = W + (size_t)(n0 + row) * LDK + lchk * 8;
  }
  int ldsW = wave * 2048;            // u16 offset of this wave's 32-row stripe

  int aoff[8], boff[4];
#pragma unroll
  for (int mt = 0; mt < 8; ++mt) {
    int r = wm + mt * 16 + r16;
    aoff[mt] = r * 64 + (quad ^ (r16 & 7)) * 8;
  }
#pragma unroll
  for (int nt = 0; nt < 4; ++nt) {
    int r = wn + nt * 16 + r16;
    boff[nt] = r * 64 + (quad ^ (r16 & 7)) * 8;
  }

#define ISSUE_TILE(t, buf)                                                              \
  do {                                                                                  \
    int _o = (buf) * 16384 + ldsW, _k = (t) * 64;                                       \
    __builtin_amdgcn_global_load_lds(GLB_PTR(Ag[0] + _k), LDS_PTR(Asm + _o),        16, 0, 0); \
    __builtin_amdgcn_global_load_lds(GLB_PTR(Ag[1] + _k), LDS_PTR(Asm + _o + 512),  16, 0, 0); \
    __builtin_amdgcn_global_load_lds(GLB_PTR(Ag[2] + _k), LDS_PTR(Asm + _o + 1024), 16, 0, 0); \
    __builtin_amdgcn_global_load_lds(GLB_PTR(Ag[3] + _k), LDS_PTR(Asm + _o + 1536), 16, 0, 0); \
    __builtin_amdgcn_global_load_lds(GLB_PTR(Bg[0] + _k), LDS_PTR(Bsm + _o),        16, 0, 0); \
    __builtin_amdgcn_global_load_lds(GLB_PTR(Bg[1] + _k), LDS_PTR(Bsm + _o + 512),  16, 0, 0); \
    __builtin_amdgcn_global_load_lds(GLB_PTR(Bg[2] + _k), LDS_PTR(Bsm + _o + 1024), 16, 0, 0); \
    __builtin_amdgcn_global_load_lds(GLB_PTR(Bg[3] + _k), LDS_PTR(Bsm + _o + 1536), 16, 0, 0); \
  } while (0)

  ISSUE_TILE(0, 0);
  ISSUE_TILE(1, 1);                  // 16 loads outstanding

  int cur = 0;
  for (int i = 0; i < KITER; ++i) {
    if (i < KITER - 1) asm volatile("s_waitcnt vmcnt(8)" ::: "memory");
    else               asm volatile("s_waitcnt vmcnt(0)" ::: "memory");
    __builtin_amdgcn_s_barrier();    // all waves' tile-i data landed

    const u16* As = Asm + cur * 16384;
    const u16* Bs = Bsm + cur * 16384;
#pragma unroll
    for (int kk = 0; kk < 2; ++kk) {
      int kx = kk * 32;              // chunk ^4 == u16 offset ^32
      bf16x8 af[8], bfm[4];
#pragma unroll
      for (int mt = 0; mt < 8; ++mt) af[mt] = *(const bf16x8*)&As[aoff[mt] ^ kx];
#pragma unroll
      for (int nt = 0; nt < 4; ++nt) bfm[nt] = *(const bf16x8*)&Bs[boff[nt] ^ kx];
#pragma unroll
      for (int mt = 0; mt < 8; ++mt)
#pragma unroll
        for (int nt = 0; nt < 4; ++nt)
          acc[mt][nt] = __builtin_amdgcn_mfma_f32_16x16x32_bf16(af[mt], bfm[nt], acc[mt][nt], 0, 0, 0);
    }

    asm volatile("s_waitcnt lgkmcnt(0)" ::: "memory");  // my ds_reads done
    __builtin_amdgcn_s_barrier();                       // everyone's reads done
    if (i + 2 < KITER) ISSUE_TILE(i + 2, cur);          // re-target freed buffer
    cur ^= 1;
  }
#undef ISSUE_TILE

  // epilogue: C/D layout col=lane&15, row=quad*4+reg  [verified m89/m91]
#pragma unroll
  for (int mt = 0; mt < 8; ++mt) {
#pragma unroll
    for (int nt = 0; nt < 4; ++nt) {
#pragma unroll
      for (int rg = 0; rg < 4; ++rg) {
        int row = m0 + wm + mt * 16 + quad * 4 + rg;
        int col = n0 + wn + nt * 16 + r16;
        float v = acc[mt][nt][rg];
        size_t idx = (size_t)row * 1024 + col;
        if (mat == 0)      rO[idx] = f2bf(1.f / (1.f + __expf(-v)));
        else if (mat == 1) kO[idx] = f2bf(v);
        else if (mat == 2) vO[idx] = f2bf(v);
        else               wO[idx] = v;   // raw z; sigmoid folded into scan
      }
    }
  }
}

// ---------------- K5: output GEMM, in-block split-K (LDS reduce) ------------
// 1-D grid 256; XCD decode groups the 8 n-blocks sharing an A-panel (same x)
// onto one XCD (XCD k gets x in {k, k+8, k+16, k+24}).
__global__ __launch_bounds__(512, 1) void gemm_out_sk(
    const u16* __restrict__ A, const u16* __restrict__ W,
    float* __restrict__ O) {
  constexpr int KITER = 8;           // 512 / 64
  constexpr int LDK   = 1024;
  __shared__ __align__(16) u16 SMEM[2][2][2][8192];

  int d  = blockIdx.x;               // 0..255
  int k8 = d & 7, q = d >> 3;        // q in [0,32)
  int gh = q >> 3;                   // 0..3
  int yt = q & 7;                    // n-tile 0..7
  int xt = k8 + 8 * gh;              // m-tile 0..31

  int tid = threadIdx.x;
  int m0 = xt * 128, n0 = yt * 128;
  int wave = tid >> 6, lane = tid & 63;
  int grp = wave >> 2, w4 = wave & 3;
  int wm = (w4 >> 1) * 64, wn = (w4 & 1) * 64;
  int r16 = lane & 15, quad = lane >> 4;

  f32x4 acc[4][4] = {};

  int lrow  = lane >> 3;             // 0..7
  int lchk  = (lane & 7) ^ lrow;     // swizzled source chunk
  const u16* Ag[4];
  const u16* Bg[4];
#pragma unroll
  for (int i = 0; i < 4; ++i) {
    int row = w4 * 32 + i * 8 + lrow;
    Ag[i] = A + (size_t)(m0 + row) * LDK + grp * 512 + lchk * 8;
    Bg[i] = W + (size_t)(n0 + row) * LDK + grp * 512 + lchk * 8;
  }
  u16* Abase = &SMEM[0][grp][0][0];
  u16* Bbase = &SMEM[1][grp][0][0];
  int ldsW = w4 * 2048;              // u16 offset of this wave's 32-row stripe

  int aoff[4], boff[4];
#pragma unroll
  for (int mt = 0; mt < 4; ++mt) {
    int r = wm + mt * 16 + r16;
    aoff[mt] = r * 64 + (quad ^ (r16 & 7)) * 8;
  }
#pragma unroll
  for (int nt = 0; nt < 4; ++nt) {
    int r = wn + nt * 16 + r16;
    boff[nt] = r * 64 + (quad ^ (r16 & 7)) * 8;
  }

#define ISSUE_TILE(t, buf)                                                              \
  do {                                                                                  \
    int _o = (buf) * 8192 + ldsW, _k = (t) * 64;                                        \
    __builtin_amdgcn_global_load_lds(GLB_PTR(Ag[0] + _k), LDS_PTR(Abase + _o),        16, 0, 0); \
    __builtin_amdgcn_global_load_lds(GLB_PTR(Ag[1] + _k), LDS_PTR(Abase + _o + 512),  16, 0, 0); \
    __builtin_amdgcn_global_load_lds(GLB_PTR(Ag[2] + _k), LDS_PTR(Abase + _o + 1024), 16, 0, 0); \
    __builtin_amdgcn_global_load_lds(GLB_PTR(Ag[3] + _k), LDS_PTR(Abase + _o + 1536), 16, 0, 0); \
    __builtin_amdgcn_global_load_lds(GLB_PTR(Bg[0] + _k), LDS_PTR(Bbase + _o),        16, 0, 0); \
    __builtin_amdgcn_global_load_lds(GLB_PTR(Bg[1] + _k), LDS_PTR(Bbase + _o + 512),  16, 0, 0); \
    __builtin_amdgcn_global_load_lds(GLB_PTR(Bg[2] + _k), LDS_PTR(Bbase + _o + 1024), 16, 0, 0); \
    __builtin_amdgcn_global_load_lds(GLB_PTR(Bg[3] + _k), LDS_PTR(Bbase + _o + 1536), 16, 0, 0); \
  } while (0)

  ISSUE_TILE(0, 0);
  ISSUE_TILE(1, 1);                  // 16 loads outstanding per wave

  int cur = 0;
  for (int i = 0; i < KITER; ++i) {
    if (i < KITER - 1) asm volatile("s_waitcnt vmcnt(8)" ::: "memory");
    else               asm volatile("s_waitcnt vmcnt(0)" ::: "memory");
    __builtin_amdgcn_s_barrier();    // all waves' tile-i data landed

    const u16* As = Abase + cur * 8192;
    const u16* Bs = Bbase + cur * 8192;
#pragma unroll
    for (int kk = 0; kk < 2; ++kk) {
      int kx = kk * 32;
      bf16x8 af[4], bfm[4];
#pragma unroll
      for (int mt = 0; mt < 4; ++mt) af[mt] = *(const bf16x8*)&As[aoff[mt] ^ kx];
#pragma unroll
      for (int nt = 0; nt < 4; ++nt) bfm[nt] = *(const bf16x8*)&Bs[boff[nt] ^ kx];
#pragma unroll
      for (int mt = 0; mt < 4; ++mt)
#pragma unroll
        for (int nt = 0; nt < 4; ++nt)
          acc[mt][nt] = __builtin_amdgcn_mfma_f32_16x16x32_bf16(af[mt], bfm[nt], acc[mt][nt], 0, 0, 0);
    }

    asm volatile("s_waitcnt lgkmcnt(0)" ::: "memory");
    __builtin_amdgcn_s_barrier();
    if (i + 2 < KITER) ISSUE_TILE(i + 2, cur);
    cur ^= 1;
  }
#undef ISSUE_TILE

  // split-K reduction through LDS (staging buffers are dead now).
  float* red = (float*)&SMEM[0][0][0][0];   // 32768 floats available
  int slot = (tid & 255) * 68;              // 68-pad breaks bank alignment
  if (grp == 1) {
#pragma unroll
    for (int mt = 0; mt < 4; ++mt)
#pragma unroll
      for (int nt = 0; nt < 4; ++nt)
        *(f32x4*)&red[slot + (mt * 4 + nt) * 4] = acc[mt][nt];
  }
  __syncthreads();
  if (grp == 0) {
#pragma unroll
    for (int mt = 0; mt < 4; ++mt) {
#pragma unroll
      for (int nt = 0; nt < 4; ++nt) {
        f32x4 other = *(const f32x4*)&red[slot + (mt * 4 + nt) * 4];
#pragma unroll
        for (int rg = 0; rg < 4; ++rg) {
          int row = m0 + wm + mt * 16 + quad * 4 + rg;
          int col = n0 + wn + nt * 16 + r16;
          O[(size_t)row * 1024 + col] = acc[mt][nt][rg] + other[rg];
        }
      }
    }
  }
}

// ---------------- K2: intra-chunk scan, C=32, 16x16 thread map --------------
__global__ __launch_bounds__(256) void scan_intra(
    const u16* __restrict__ rb, const u16* __restrict__ kb,
    const u16* __restrict__ vb, const float* __restrict__ wb,
    const float* __restrict__ u,
    float* __restrict__ o, u16* __restrict__ rd,
    float* __restrict__ U, float* __restrict__ Dc) {
  int c = blockIdx.x, bh = blockIdx.y;
  int b = bh >> 4, h = bh & 15;
  int tid = threadIdx.x;
  int wave = tid >> 6, lane = tid & 63;
  int ig4 = tid >> 4, jq = tid & 15;

  __shared__ __align__(16) float4 combo[4][64];  // per-i: (r, k, exp(u+k), ew)
  __shared__ __align__(16) float4 vs4[4][16];    // v, viewed 4-wide
  __shared__ __align__(16) float  part[4][16][68];

  const float EW_SCALE = 0.99990001f;  // exp(-1e-4)

  float s[4][4];
#pragma unroll
  for (int ii = 0; ii < 4; ++ii)
#pragma unroll
    for (int jj = 0; jj < 4; ++jj) s[ii][jj] = 0.f;

  size_t base = ((size_t)(b * 1024 + c * 32)) * 1024 + h * 64 + lane;
  float dloc = 1.0f;
  float uval = (wave < 2) ? u[h * 64 + lane] : 0.f;   // combo stagers: i==lane

#define STAGE(t2, sl)                                                     \
  do {                                                                    \
    size_t _idx = base + (size_t)(t2) * 1024;                             \
    if (wave < 2) {                                                       \
      float _r = bf2f(rb[_idx]);                                          \
      float _k = bf2f(kb[_idx]);                                          \
      float _z = wb[_idx];                                                \
      combo[sl][lane] = make_float4(_r, _k, __expf(uval + _k),            \
                                    EW_SCALE / (1.f + __expf(-_z)));      \
    } else {                                                              \
      ((float*)vs4)[(sl) * 64 + lane] = bf2f(vb[_idx]);                   \
    }                                                                     \
  } while (0)

  // prologue: stage steps 0,1 (wave parity picks the step)
  { int p = wave & 1; STAGE(p, p); }
  __syncthreads();

  for (int tt = 0; tt < 32; tt += 2) {
    if (tt + 2 < 32) {
      int p = wave & 1;
      int t2 = tt + 2 + p;
      STAGE(t2, t2 & 3);
    }
    // compute steps tt, tt+1 (slots staged last interval, barrier crossed)
#pragma unroll
    for (int p = 0; p < 2; ++p) {
      int t = tt + p, sl = t & 3;
      float4 vv = vs4[sl][jq];
      float4 cb0 = combo[sl][ig4 * 4 + 0];
      float4 cb1 = combo[sl][ig4 * 4 + 1];
      float4 cb2 = combo[sl][ig4 * 4 + 2];
      float4 cb3 = combo[sl][ig4 * 4 + 3];
      float ac0 = 0.f, ac1 = 0.f, ac2 = 0.f, ac3 = 0.f;
#define ROW(cb, ii)                                                       \
      do {                                                                \
        float t0 = fmaf(cb.z, vv.x, s[ii][0]);                            \
        float t1 = fmaf(cb.z, vv.y, s[ii][1]);                            \
        float t2_ = fmaf(cb.z, vv.z, s[ii][2]);                           \
        float t3 = fmaf(cb.z, vv.w, s[ii][3]);                            \
        ac0 = fmaf(cb.x, t0, ac0);                                        \
        ac1 = fmaf(cb.x, t1, ac1);                                        \
        ac2 = fmaf(cb.x, t2_, ac2);                                       \
        ac3 = fmaf(cb.x, t3, ac3);                                        \
        s[ii][0] = fmaf(cb.w, s[ii][0], cb.y * vv.x);                     \
        s[ii][1] = fmaf(cb.w, s[ii][1], cb.y * vv.y);                     \
        s[ii][2] = fmaf(cb.w, s[ii][2], cb.y * vv.z);                     \
        s[ii][3] = fmaf(cb.w, s[ii][3], cb.y * vv.w);                     \
      } while (0)
      ROW(cb0, 0); ROW(cb1, 1); ROW(cb2, 2); ROW(cb3, 3);
#undef ROW
      *(float4*)&part[sl][ig4][jq * 4] = make_float4(ac0, ac1, ac2, ac3);
      if (wave == 0) {
        float4 me = combo[sl][lane];          // i == lane, vector b128
        rd[base + (size_t)t * 1024] = f2bf(me.x * dloc);
        dloc *= me.w;
      }
    }
    // store o for steps tt-2, tt-1 (parts complete since last barrier)
    if (tt >= 2) {
      if (wave == 2) {
        int t = tt - 2, sl = t & 3;
        float sum = 0.f;
#pragma unroll
        for (int g = 0; g < 16; ++g) sum += part[sl][g][lane];
        o[base + (size_t)t * 1024] = sum;
      } else if (wave == 3) {
        int t = tt - 1, sl = t & 3;
        float sum = 0.f;
#pragma unroll
        for (int g = 0; g < 16; ++g) sum += part[sl][g][lane];
        o[base + (size_t)t * 1024] = sum;
      }
    }
    __syncthreads();
  }
#undef STAGE
  // final two steps' o (slots 30&3=2, 31&3=3)
  if (wave == 2) {
    float sum = 0.f;
#pragma unroll
    for (int g = 0; g < 16; ++g) sum += part[2][g][lane];
    o[base + (size_t)30 * 1024] = sum;
  } else if (wave == 3) {
    float sum = 0.f;
#pragma unroll
    for (int g = 0; g < 16; ++g) sum += part[3][g][lane];
    o[base + (size_t)31 * 1024] = sum;
  }

  float* Ug = U + (size_t)(bh * 32 + c) * 4096;
#pragma unroll
  for (int ii = 0; ii < 4; ++ii) {
    *(float4*)&Ug[(ig4 * 4 + ii) * 64 + jq * 4] =
        make_float4(s[ii][0], s[ii][1], s[ii][2], s[ii][3]);
  }
  if (wave == 0) Dc[(bh * 32 + c) * 64 + lane] = dloc;
}

// ---------------- K3: chunk-state propagation -> bf16 S_c -------------------
// Reads U (fp32, unchanged), writes S_c as bf16 into ST (dead wbuf region).
// inter_ln previously cast S->bf16 for MFMA anyway: bit-identical math.
__global__ __launch_bounds__(256) void state_prop(
    const float* __restrict__ U, const float* __restrict__ Dc,
    u16* __restrict__ ST) {
  int bh  = blockIdx.x >> 4;
  int e   = (blockIdx.x & 15) * 256 + threadIdx.x;  // 0..4095
  int i   = e >> 6;
  float acc = 0.f;
  for (int c = 0; c < 32; ++c) {
    float d  = Dc[(bh * 32 + c) * 64 + i];
    float uv = U[(size_t)(bh * 32 + c) * 4096 + e];
    ST[(size_t)(bh * 32 + c) * 4096 + e] = f2bf(acc);  // S_c (chunk-initial)
    acc = fmaf(d, acc, uv);                            // S_{c+1} = D*S + U
  }
}

// ---------------- K4: O = o_intra + RD@S_c (MFMA) + group-LN + gate --------
__global__ __launch_bounds__(128) void inter_ln(
    const float* __restrict__ o, const u16* __restrict__ rd,
    const u16* __restrict__ rb, const u16* __restrict__ ST,
    const float* __restrict__ lnw, const float* __restrict__ lnb,
    u16* __restrict__ oh) {
  int c = blockIdx.x, bh = blockIdx.y;
  int b = bh >> 4, h = bh & 15;
  int tid = threadIdx.x, wave = tid >> 6, lane = tid & 63;
  int l15 = lane & 15, quad = lane >> 4;

  __shared__ __align__(16) u16 Sb[64][72];   // Sb[j][i] = S_c[i][j] (bf16)

  const u16* Sg = ST + (size_t)(bh * 32 + c) * 4096;
#pragma unroll
  for (int q = 0; q < 32; ++q) {
    int e = q * 128 + tid;
    Sb[e & 63][e >> 6] = Sg[e];
  }
  __syncthreads();

  size_t rbase = ((size_t)(b * 1024 + c * 32)) * 1024 + h * 64;

  const u16* rdg = rd + rbase + (size_t)(wave * 16 + l15) * 1024 + quad * 8;
  bf16x8 af0 = *(const bf16x8*)(rdg);
  bf16x8 af1 = *(const bf16x8*)(rdg + 32);

  f32x4 acc[4] = {};
#pragma unroll
  for (int nt = 0; nt < 4; ++nt) {
    const u16* bp = &Sb[nt * 16 + l15][quad * 8];
    bf16x8 b0 = *(const bf16x8*)bp;
    bf16x8 b1 = *(const bf16x8*)(bp + 32);
    acc[nt] = __builtin_amdgcn_mfma_f32_16x16x32_bf16(af0, b0, acc[nt], 0, 0, 0);
    acc[nt] = __builtin_amdgcn_mfma_f32_16x16x32_bf16(af1, b1, acc[nt], 0, 0, 0);
  }

#pragma unroll
  for (int rg = 0; rg < 4; ++rg) {
    int t = wave * 16 + quad * 4 + rg;
    size_t rowb = rbase + (size_t)t * 1024;
    float v[4];
    float s1 = 0.f, s2 = 0.f;
#pragma unroll
    for (int nt = 0; nt < 4; ++nt) {
      v[nt] = acc[nt][rg] + o[rowb + nt * 16 + l15];
      s1 += v[nt];
      s2 += v[nt] * v[nt];
    }
#pragma unroll
    for (int m = 1; m < 16; m <<= 1) {   // reduce across the quad's 16 lanes
      s1 += __shfl_xor(s1, m, 64);
      s2 += __shfl_xor(s2, m, 64);
    }
    float mu  = s1 * (1.f / 64.f);
    float var = s2 * (1.f / 64.f) - mu * mu;
    float rstd = rsqrtf(var + 1e-5f);
#pragma unroll
    for (int nt = 0; nt < 4; ++nt) {
      int jj = nt * 16 + l15;
      float nv = (v[nt] - mu) * rstd;
      float val = (nv * lnw[jj] + lnb[jj]) * bf2f(rb[rowb + jj]);
      oh[rowb + jj] = f2bf(val);
    }
  }
}

// ---------------- launch -----------------------------------------------------
extern "C" void kernel_launch(void* const* d_in, const int* in_sizes, int n_in,
                              void* d_out, int out_size, void* d_ws, size_t ws_size,
                              hipStream_t stream) {
  const float* x    = (const float*)d_in[0];
  const float* W_r  = (const float*)d_in[1];
  const float* W_k  = (const float*)d_in[2];
  const float* W_v  = (const float*)d_in[3];
  const float* W_w  = (const float*)d_in[4];
  const float* W_o  = (const float*)d_in[5];
  const float* u    = (const float*)d_in[6];
  const float* tm_r = (const float*)d_in[7];
  const float* tm_k = (const float*)d_in[8];
  const float* tm_v = (const float*)d_in[9];
  const float* tm_w = (const float*)d_in[10];
  const float* ln_w = (const float*)d_in[11];
  const float* ln_b = (const float*)d_in[12];
  float* out = (float*)d_out;

  char* ws = (char*)d_ws;
  // region [0,32)MB: xr..xw during prep/gemm_proj; reused as Ubuf afterwards
  u16* xr = (u16*)(ws + (size_t)0 * MB);
  u16* xk = (u16*)(ws + (size_t)8 * MB);
  u16* xv = (u16*)(ws + (size_t)16 * MB);
  u16* xw = (u16*)(ws + (size_t)24 * MB);
  float* Ubuf = (float*)(ws + (size_t)0 * MB);   // 32MB (64bh x 32c x 4096)
  u16* Wb = (u16*)(ws + (size_t)32 * MB);   // 5 x 2MB: Wr,Wk,Wv,Ww,Wo
  u16* Wrb = Wb;
  u16* Wkb = (u16*)(ws + (size_t)34 * MB);
  u16* Wvb = (u16*)(ws + (size_t)36 * MB);
  u16* Wwb = (u16*)(ws + (size_t)38 * MB);
  u16* Wob = (u16*)(ws + (size_t)40 * MB);
  float* Dcbuf = (float*)(ws + (size_t)42 * MB); // 512KB (64bh x 32c x 64)
  u16*   rbuf = (u16*)(ws + (size_t)48 * MB);    // 8MB bf16
  u16*   kbuf = (u16*)(ws + (size_t)56 * MB);    // 8MB bf16
  u16*   vbuf = (u16*)(ws + (size_t)64 * MB);    // 8MB bf16
  float* wbuf = (float*)(ws + (size_t)72 * MB);  // 16MB fp32 (raw z for decay)
  u16*   Sbuf = (u16*)(ws + (size_t)72 * MB);    // 16MB bf16 S_c — reuses wbuf
                                                 // (wbuf dead after scan_intra)
  float* obuf = (float*)(ws + (size_t)88 * MB);  // 16MB fp32 o_intra
  u16*  rdbuf = (u16*)(ws + (size_t)104 * MB);   // 8MB bf16
  u16*   ohbuf = (u16*)(ws + (size_t)129 * MB);  // 8MB

  prep_all<<<18432, 256, 0, stream>>>(W_r, W_k, W_v, W_w, W_o, (u32*)Wb,
                                      x, tm_r, tm_k, tm_v, tm_w,
                                      (u32*)xr, (u32*)xk, (u32*)xv, (u32*)xw);
  gemm_proj<<<256, 512, 0, stream>>>(xr, xk, xv, xw,
                                     Wrb, Wkb, Wvb, Wwb,
                                     rbuf, kbuf, vbuf, wbuf);
  scan_intra<<<dim3(32, 64), 256, 0, stream>>>(rbuf, kbuf, vbuf, wbuf, u,
                                               obuf, rdbuf, Ubuf, Dcbuf);
  state_prop<<<1024, 256, 0, stream>>>(Ubuf, Dcbuf, Sbuf);
  inter_ln<<<dim3(32, 64), 128, 0, stream>>>(obuf, rdbuf, rbuf, Sbuf,
                                             ln_w, ln_b, ohbuf);
  gemm_out_sk<<<256, 512, 0, stream>>>(ohbuf, Wob, out);
}

// Round 13
// 229.925 us; speedup vs baseline: 1.1066x; 1.0127x over previous
//
#include <hip/hip_runtime.h>

// RWKV6 TimeMix on MI355X — R18: fix R17's crash. R17 reverted gemm_out_sk's
// BODY to the 2-D-grid form (m0=bx*128, n0=by*128) but kept R16's 1-D launch
// <<<256>>> -> blockIdx.y==0, m0 up to 32640 >> M=4096 -> OOB reads/writes ->
// abort. Fix: launch gemm_out_sk<<<dim3(32,8), 512>>>. No other change.
// Content (from R17): plain 3-D grids on both GEMMs (XCD swizzle reverted per
// R16 counters), S_c bf16, o_intra bf16, merged prep.
//
//   K0 prep_all    : weights fp32->bf16 + token-shift mix (merged)
//   K1 gemm_proj   : 4 projections (z-grid), 256^2/8-wave/BK64 MFMA
//   K2 scan_intra  : chunked (C=32) scan -> o_intra (bf16), rd, U_c, D_c
//   K3 state_prop  : S_{c+1} = D_c*S_c + U_c; writes S_c as bf16
//   K4 inter_ln    : O = o_intra + RD@S_c (MFMA), group-LN, *r -> oh (bf16)
//   K5 gemm_out_sk : 128^2 tile, 2 K-groups x 4 waves, LDS reduce -> d_out
//
// Shapes: B=4, T=1024, D=1024, H=16, DH=64. Chunks: NC=32, C=32.

typedef unsigned short u16;
typedef unsigned int   u32;

typedef __attribute__((ext_vector_type(8))) __bf16 bf16x8;
typedef __attribute__((ext_vector_type(4))) float   f32x4;

#define MB (1u << 20)

#define LDS_PTR(p) ((__attribute__((address_space(3))) void*)(p))
#define GLB_PTR(p) ((const __attribute__((address_space(1))) void*)(p))

__device__ __forceinline__ u16 f2bf(float f) {
  u32 u = __builtin_bit_cast(u32, f);
  u += 0x7FFFu + ((u >> 16) & 1u);   // RNE; inputs are finite
  return (u16)(u >> 16);
}
__device__ __forceinline__ float bf2f(u16 x) {
  u32 u = ((u32)x) << 16;
  return __builtin_bit_cast(float, u);
}
__device__ __forceinline__ u32 pack2(float a, float b) {
  return (u32)f2bf(a) | ((u32)f2bf(b) << 16);
}

// ---------------- K0: merged weight-cast + token-shift mix ------------------
__global__ __launch_bounds__(256) void prep_all(
    const float* __restrict__ w0, const float* __restrict__ w1,
    const float* __restrict__ w2, const float* __restrict__ w3,
    const float* __restrict__ w4, u32* __restrict__ wout,
    const float* __restrict__ x,
    const float* __restrict__ tmr, const float* __restrict__ tmk,
    const float* __restrict__ tmv, const float* __restrict__ tmw,
    u32* __restrict__ xr, u32* __restrict__ xk,
    u32* __restrict__ xv, u32* __restrict__ xw) {
  int bid = blockIdx.x;
  if (bid < 10240) {                          // weight cast: 5 x 524288 pairs
    int idx = bid * 256 + threadIdx.x;
    int m = idx >> 19;
    int l = idx & 524287;
    const float* src = (m == 0) ? w0 : (m == 1) ? w1 : (m == 2) ? w2 : (m == 3) ? w3 : w4;
    float2 v = *(const float2*)(src + (size_t)l * 2);
    wout[idx] = pack2(v.x, v.y);
  } else {                                    // token-shift mix
    int idx = (bid - 10240) * 256 + threadIdx.x;  // pair index over 4*1024*512
    int t  = (idx >> 9) & 1023;
    int d0 = (idx & 511) * 2;
    size_t e = (size_t)idx * 2;
    float2 xc = *(const float2*)(x + e);
    float2 xp = make_float2(0.f, 0.f);
    if (t > 0) xp = *(const float2*)(x + e - 1024);
    float2 tm;
    tm = *(const float2*)(tmr + d0);
    xr[idx] = pack2(tm.x * xc.x + (1.f - tm.x) * xp.x, tm.y * xc.y + (1.f - tm.y) * xp.y);
    tm = *(const float2*)(tmk + d0);
    xk[idx] = pack2(tm.x * xc.x + (1.f - tm.x) * xp.x, tm.y * xc.y + (1.f - tm.y) * xp.y);
    tm = *(const float2*)(tmv + d0);
    xv[idx] = pack2(tm.x * xc.x + (1.f - tm.x) * xp.x, tm.y * xc.y + (1.f - tm.y) * xp.y);
    tm = *(const float2*)(tmw + d0);
    xw[idx] = pack2(tm.x * xc.x + (1.f - tm.x) * xp.x, tm.y * xc.y + (1.f - tm.y) * xp.y);
  }
}

// ---------------- K1: 256x256xBK64 8-wave projection GEMM (proven core) -----
__global__ __launch_bounds__(512, 1) void gemm_proj(
    const u16* __restrict__ xr, const u16* __restrict__ xk,
    const u16* __restrict__ xv, const u16* __restrict__ xw,
    const u16* __restrict__ Wr, const u16* __restrict__ Wk,
    const u16* __restrict__ Wv, const u16* __restrict__ Ww,
    u16* __restrict__ rO, u16* __restrict__ kO,
    u16* __restrict__ vO, float* __restrict__ wO) {
  constexpr int KITER = 16;          // K = 1024 / 64
  constexpr int LDK   = 1024;        // u16 row stride of A and W
  __shared__ __align__(16) u16 Asm[2 * 16384];   // 2 x 32KB ([256][64] u16)
  __shared__ __align__(16) u16 Bsm[2 * 16384];   // 2 x 32KB

  int mat = blockIdx.z;              // uniform
  const u16* A = (mat == 0) ? xr : (mat == 1) ? xk : (mat == 2) ? xv : xw;
  const u16* W = (mat == 0) ? Wr : (mat == 1) ? Wk : (mat == 2) ? Wv : Ww;

  int tid = threadIdx.x;
  int m0 = blockIdx.x * 256, n0 = blockIdx.y * 256;
  int wave = tid >> 6, lane = tid & 63;
  int wm = (wave >> 2) * 128;        // {0,128}
  int wn = (wave & 3) * 64;          // {0,64,128,192}
  int r16 = lane & 15, quad = lane >> 4;

  f32x4 acc[8][4] = {};

  int lrow  = lane >> 3;             // 0..7
  int lchk  = (lane & 7) ^ lrow;     // swizzled source chunk
  const u16* Ag[4];
  const u16* Bg[4];
#pragma unroll
  for (int i = 0; i < 4; ++i) {
    int row = wave * 32 + i * 8 + lrow;
    Ag[i] = A + (size_t)(m0 + row) * LDK + lchk * 8;
    Bg[i] = W + (size_t)(n0 + row) * LDK + lchk * 8;
  }
  int ldsW = wave * 2048;            // u16 offset of this wave's 32-row stripe

  int aoff[8], boff[4];
#pragma unroll
  for (int mt = 0; mt < 8; ++mt) {
    int r = wm + mt * 16 + r16;
    aoff[mt] = r * 64 + (quad ^ (r16 & 7)) * 8;
  }
#pragma unroll
  for (int nt = 0; nt < 4; ++nt) {
    int r = wn + nt * 16 + r16;
    boff[nt] = r * 64 + (quad ^ (r16 & 7)) * 8;
  }

#define ISSUE_TILE(t, buf)                                                              \
  do {                                                                                  \
    int _o = (buf) * 16384 + ldsW, _k = (t) * 64;                                       \
    __builtin_amdgcn_global_load_lds(GLB_PTR(Ag[0] + _k), LDS_PTR(Asm + _o),        16, 0, 0); \
    __builtin_amdgcn_global_load_lds(GLB_PTR(Ag[1] + _k), LDS_PTR(Asm + _o + 512),  16, 0, 0); \
    __builtin_amdgcn_global_load_lds(GLB_PTR(Ag[2] + _k), LDS_PTR(Asm + _o + 1024), 16, 0, 0); \
    __builtin_amdgcn_global_load_lds(GLB_PTR(Ag[3] + _k), LDS_PTR(Asm + _o + 1536), 16, 0, 0); \
    __builtin_amdgcn_global_load_lds(GLB_PTR(Bg[0] + _k), LDS_PTR(Bsm + _o),        16, 0, 0); \
    __builtin_amdgcn_global_load_lds(GLB_PTR(Bg[1] + _k), LDS_PTR(Bsm + _o + 512),  16, 0, 0); \
    __builtin_amdgcn_global_load_lds(GLB_PTR(Bg[2] + _k), LDS_PTR(Bsm + _o + 1024), 16, 0, 0); \
    __builtin_amdgcn_global_load_lds(GLB_PTR(Bg[3] + _k), LDS_PTR(Bsm + _o + 1536), 16, 0, 0); \
  } while (0)

  ISSUE_TILE(0, 0);
  ISSUE_TILE(1, 1);                  // 16 loads outstanding

  int cur = 0;
  for (int i = 0; i < KITER; ++i) {
    if (i < KITER - 1) asm volatile("s_waitcnt vmcnt(8)" ::: "memory");
    else               asm volatile("s_waitcnt vmcnt(0)" ::: "memory");
    __builtin_amdgcn_s_barrier();    // all waves' tile-i data landed

    const u16* As = Asm + cur * 16384;
    const u16* Bs = Bsm + cur * 16384;
#pragma unroll
    for (int kk = 0; kk < 2; ++kk) {
      int kx = kk * 32;              // chunk ^4 == u16 offset ^32
      bf16x8 af[8], bfm[4];
#pragma unroll
      for (int mt = 0; mt < 8; ++mt) af[mt] = *(const bf16x8*)&As[aoff[mt] ^ kx];
#pragma unroll
      for (int nt = 0; nt < 4; ++nt) bfm[nt] = *(const bf16x8*)&Bs[boff[nt] ^ kx];
#pragma unroll
      for (int mt = 0; mt < 8; ++mt)
#pragma unroll
        for (int nt = 0; nt < 4; ++nt)
          acc[mt][nt] = __builtin_amdgcn_mfma_f32_16x16x32_bf16(af[mt], bfm[nt], acc[mt][nt], 0, 0, 0);
    }

    asm volatile("s_waitcnt lgkmcnt(0)" ::: "memory");  // my ds_reads done
    __builtin_amdgcn_s_barrier();                       // everyone's reads done
    if (i + 2 < KITER) ISSUE_TILE(i + 2, cur);          // re-target freed buffer
    cur ^= 1;
  }
#undef ISSUE_TILE

  // epilogue: C/D layout col=lane&15, row=quad*4+reg  [verified m89/m91]
#pragma unroll
  for (int mt = 0; mt < 8; ++mt) {
#pragma unroll
    for (int nt = 0; nt < 4; ++nt) {
#pragma unroll
      for (int rg = 0; rg < 4; ++rg) {
        int row = m0 + wm + mt * 16 + quad * 4 + rg;
        int col = n0 + wn + nt * 16 + r16;
        float v = acc[mt][nt][rg];
        size_t idx = (size_t)row * 1024 + col;
        if (mat == 0)      rO[idx] = f2bf(1.f / (1.f + __expf(-v)));
        else if (mat == 1) kO[idx] = f2bf(v);
        else if (mat == 2) vO[idx] = f2bf(v);
        else               wO[idx] = v;   // raw z; sigmoid folded into scan
      }
    }
  }
}

// ---------------- K5: output GEMM, in-block split-K (LDS reduce) ------------
// M=4096, N=1024, K=1024. Tile 128x128; 512 thr = 2 K-groups x 4 waves.
// Grid dim3(32,8) = 256 blocks = 1/CU.  (R17 bug: was launched 1-D.)
__global__ __launch_bounds__(512, 1) void gemm_out_sk(
    const u16* __restrict__ A, const u16* __restrict__ W,
    float* __restrict__ O) {
  constexpr int KITER = 8;           // 512 / 64
  constexpr int LDK   = 1024;
  __shared__ __align__(16) u16 SMEM[2][2][2][8192];

  int tid = threadIdx.x;
  int m0 = blockIdx.x * 128, n0 = blockIdx.y * 128;
  int wave = tid >> 6, lane = tid & 63;
  int grp = wave >> 2, w4 = wave & 3;
  int wm = (w4 >> 1) * 64, wn = (w4 & 1) * 64;
  int r16 = lane & 15, quad = lane >> 4;

  f32x4 acc[4][4] = {};

  int lrow  = lane >> 3;             // 0..7
  int lchk  = (lane & 7) ^ lrow;     // swizzled source chunk
  const u16* Ag[4];
  const u16* Bg[4];
#pragma unroll
  for (int i = 0; i < 4; ++i) {
    int row = w4 * 32 + i * 8 + lrow;
    Ag[i] = A + (size_t)(m0 + row) * LDK + grp * 512 + lchk * 8;
    Bg[i] = W + (size_t)(n0 + row) * LDK + grp * 512 + lchk * 8;
  }
  u16* Abase = &SMEM[0][grp][0][0];
  u16* Bbase = &SMEM[1][grp][0][0];
  int ldsW = w4 * 2048;              // u16 offset of this wave's 32-row stripe

  int aoff[4], boff[4];
#pragma unroll
  for (int mt = 0; mt < 4; ++mt) {
    int r = wm + mt * 16 + r16;
    aoff[mt] = r * 64 + (quad ^ (r16 & 7)) * 8;
  }
#pragma unroll
  for (int nt = 0; nt < 4; ++nt) {
    int r = wn + nt * 16 + r16;
    boff[nt] = r * 64 + (quad ^ (r16 & 7)) * 8;
  }

#define ISSUE_TILE(t, buf)                                                              \
  do {                                                                                  \
    int _o = (buf) * 8192 + ldsW, _k = (t) * 64;                                        \
    __builtin_amdgcn_global_load_lds(GLB_PTR(Ag[0] + _k), LDS_PTR(Abase + _o),        16, 0, 0); \
    __builtin_amdgcn_global_load_lds(GLB_PTR(Ag[1] + _k), LDS_PTR(Abase + _o + 512),  16, 0, 0); \
    __builtin_amdgcn_global_load_lds(GLB_PTR(Ag[2] + _k), LDS_PTR(Abase + _o + 1024), 16, 0, 0); \
    __builtin_amdgcn_global_load_lds(GLB_PTR(Ag[3] + _k), LDS_PTR(Abase + _o + 1536), 16, 0, 0); \
    __builtin_amdgcn_global_load_lds(GLB_PTR(Bg[0] + _k), LDS_PTR(Bbase + _o),        16, 0, 0); \
    __builtin_amdgcn_global_load_lds(GLB_PTR(Bg[1] + _k), LDS_PTR(Bbase + _o + 512),  16, 0, 0); \
    __builtin_amdgcn_global_load_lds(GLB_PTR(Bg[2] + _k), LDS_PTR(Bbase + _o + 1024), 16, 0, 0); \
    __builtin_amdgcn_global_load_lds(GLB_PTR(Bg[3] + _k), LDS_PTR(Bbase + _o + 1536), 16, 0, 0); \
  } while (0)

  ISSUE_TILE(0, 0);
  ISSUE_TILE(1, 1);                  // 16 loads outstanding per wave

  int cur = 0;
  for (int i = 0; i < KITER; ++i) {
    if (i < KITER - 1) asm volatile("s_waitcnt vmcnt(8)" ::: "memory");
    else               asm volatile("s_waitcnt vmcnt(0)" ::: "memory");
    __builtin_amdgcn_s_barrier();    // all waves' tile-i data landed

    const u16* As = Abase + cur * 8192;
    const u16* Bs = Bbase + cur * 8192;
#pragma unroll
    for (int kk = 0; kk < 2; ++kk) {
      int kx = kk * 32;
      bf16x8 af[4], bfm[4];
#pragma unroll
      for (int mt = 0; mt < 4; ++mt) af[mt] = *(const bf16x8*)&As[aoff[mt] ^ kx];
#pragma unroll
      for (int nt = 0; nt < 4; ++nt) bfm[nt] = *(const bf16x8*)&Bs[boff[nt] ^ kx];
#pragma unroll
      for (int mt = 0; mt < 4; ++mt)
#pragma unroll
        for (int nt = 0; nt < 4; ++nt)
          acc[mt][nt] = __builtin_amdgcn_mfma_f32_16x16x32_bf16(af[mt], bfm[nt], acc[mt][nt], 0, 0, 0);
    }

    asm volatile("s_waitcnt lgkmcnt(0)" ::: "memory");
    __builtin_amdgcn_s_barrier();
    if (i + 2 < KITER) ISSUE_TILE(i + 2, cur);
    cur ^= 1;
  }
#undef ISSUE_TILE

  // split-K reduction through LDS (staging buffers are dead now).
  float* red = (float*)&SMEM[0][0][0][0];   // 32768 floats available
  int slot = (tid & 255) * 68;              // 68-pad breaks bank alignment
  if (grp == 1) {
#pragma unroll
    for (int mt = 0; mt < 4; ++mt)
#pragma unroll
      for (int nt = 0; nt < 4; ++nt)
        *(f32x4*)&red[slot + (mt * 4 + nt) * 4] = acc[mt][nt];
  }
  __syncthreads();
  if (grp == 0) {
#pragma unroll
    for (int mt = 0; mt < 4; ++mt) {
#pragma unroll
      for (int nt = 0; nt < 4; ++nt) {
        f32x4 other = *(const f32x4*)&red[slot + (mt * 4 + nt) * 4];
#pragma unroll
        for (int rg = 0; rg < 4; ++rg) {
          int row = m0 + wm + mt * 16 + quad * 4 + rg;
          int col = n0 + wn + nt * 16 + r16;
          O[(size_t)row * 1024 + col] = acc[mt][nt][rg] + other[rg];
        }
      }
    }
  }
}

// ---------------- K2: intra-chunk scan, C=32, 16x16 thread map --------------
// o_intra stored bf16 (additive pre-LN term; rounding is post-LN noise).
__global__ __launch_bounds__(256) void scan_intra(
    const u16* __restrict__ rb, const u16* __restrict__ kb,
    const u16* __restrict__ vb, const float* __restrict__ wb,
    const float* __restrict__ u,
    u16* __restrict__ o, u16* __restrict__ rd,
    float* __restrict__ U, float* __restrict__ Dc) {
  int c = blockIdx.x, bh = blockIdx.y;
  int b = bh >> 4, h = bh & 15;
  int tid = threadIdx.x;
  int wave = tid >> 6, lane = tid & 63;
  int ig4 = tid >> 4, jq = tid & 15;

  __shared__ __align__(16) float4 combo[4][64];  // per-i: (r, k, exp(u+k), ew)
  __shared__ __align__(16) float4 vs4[4][16];    // v, viewed 4-wide
  __shared__ __align__(16) float  part[4][16][68];

  const float EW_SCALE = 0.99990001f;  // exp(-1e-4)

  float s[4][4];
#pragma unroll
  for (int ii = 0; ii < 4; ++ii)
#pragma unroll
    for (int jj = 0; jj < 4; ++jj) s[ii][jj] = 0.f;

  size_t base = ((size_t)(b * 1024 + c * 32)) * 1024 + h * 64 + lane;
  float dloc = 1.0f;
  float uval = (wave < 2) ? u[h * 64 + lane] : 0.f;   // combo stagers: i==lane

#define STAGE(t2, sl)                                                     \
  do {                                                                    \
    size_t _idx = base + (size_t)(t2) * 1024;                             \
    if (wave < 2) {                                                       \
      float _r = bf2f(rb[_idx]);                                          \
      float _k = bf2f(kb[_idx]);                                          \
      float _z = wb[_idx];                                                \
      combo[sl][lane] = make_float4(_r, _k, __expf(uval + _k),            \
                                    EW_SCALE / (1.f + __expf(-_z)));      \
    } else {                                                              \
      ((float*)vs4)[(sl) * 64 + lane] = bf2f(vb[_idx]);                   \
    }                                                                     \
  } while (0)

  // prologue: stage steps 0,1 (wave parity picks the step)
  { int p = wave & 1; STAGE(p, p); }
  __syncthreads();

  for (int tt = 0; tt < 32; tt += 2) {
    if (tt + 2 < 32) {
      int p = wave & 1;
      int t2 = tt + 2 + p;
      STAGE(t2, t2 & 3);
    }
    // compute steps tt, tt+1 (slots staged last interval, barrier crossed)
#pragma unroll
    for (int p = 0; p < 2; ++p) {
      int t = tt + p, sl = t & 3;
      float4 vv = vs4[sl][jq];
      float4 cb0 = combo[sl][ig4 * 4 + 0];
      float4 cb1 = combo[sl][ig4 * 4 + 1];
      float4 cb2 = combo[sl][ig4 * 4 + 2];
      float4 cb3 = combo[sl][ig4 * 4 + 3];
      float ac0 = 0.f, ac1 = 0.f, ac2 = 0.f, ac3 = 0.f;
#define ROW(cb, ii)                                                       \
      do {                                                                \
        float t0 = fmaf(cb.z, vv.x, s[ii][0]);                            \
        float t1 = fmaf(cb.z, vv.y, s[ii][1]);                            \
        float t2_ = fmaf(cb.z, vv.z, s[ii][2]);                           \
        float t3 = fmaf(cb.z, vv.w, s[ii][3]);                            \
        ac0 = fmaf(cb.x, t0, ac0);                                        \
        ac1 = fmaf(cb.x, t1, ac1);                                        \
        ac2 = fmaf(cb.x, t2_, ac2);                                       \
        ac3 = fmaf(cb.x, t3, ac3);                                        \
        s[ii][0] = fmaf(cb.w, s[ii][0], cb.y * vv.x);                     \
        s[ii][1] = fmaf(cb.w, s[ii][1], cb.y * vv.y);                     \
        s[ii][2] = fmaf(cb.w, s[ii][2], cb.y * vv.z);                     \
        s[ii][3] = fmaf(cb.w, s[ii][3], cb.y * vv.w);                     \
      } while (0)
      ROW(cb0, 0); ROW(cb1, 1); ROW(cb2, 2); ROW(cb3, 3);
#undef ROW
      *(float4*)&part[sl][ig4][jq * 4] = make_float4(ac0, ac1, ac2, ac3);
      if (wave == 0) {
        float4 me = combo[sl][lane];          // i == lane, vector b128
        rd[base + (size_t)t * 1024] = f2bf(me.x * dloc);
        dloc *= me.w;
      }
    }
    // store o for steps tt-2, tt-1 (parts complete since last barrier)
    if (tt >= 2) {
      if (wave == 2) {
        int t = tt - 2, sl = t & 3;
        float sum = 0.f;
#pragma unroll
        for (int g = 0; g < 16; ++g) sum += part[sl][g][lane];
        o[base + (size_t)t * 1024] = f2bf(sum);
      } else if (wave == 3) {
        int t = tt - 1, sl = t & 3;
        float sum = 0.f;
#pragma unroll
        for (int g = 0; g < 16; ++g) sum += part[sl][g][lane];
        o[base + (size_t)t * 1024] = f2bf(sum);
      }
    }
    __syncthreads();
  }
#undef STAGE
  // final two steps' o (slots 30&3=2, 31&3=3)
  if (wave == 2) {
    float sum = 0.f;
#pragma unroll
    for (int g = 0; g < 16; ++g) sum += part[2][g][lane];
    o[base + (size_t)30 * 1024] = f2bf(sum);
  } else if (wave == 3) {
    float sum = 0.f;
#pragma unroll
    for (int g = 0; g < 16; ++g) sum += part[3][g][lane];
    o[base + (size_t)31 * 1024] = f2bf(sum);
  }

  float* Ug = U + (size_t)(bh * 32 + c) * 4096;
#pragma unroll
  for (int ii = 0; ii < 4; ++ii) {
    *(float4*)&Ug[(ig4 * 4 + ii) * 64 + jq * 4] =
        make_float4(s[ii][0], s[ii][1], s[ii][2], s[ii][3]);
  }
  if (wave == 0) Dc[(bh * 32 + c) * 64 + lane] = dloc;
}

// ---------------- K3: chunk-state propagation -> bf16 S_c -------------------
__global__ __launch_bounds__(256) void state_prop(
    const float* __restrict__ U, const float* __restrict__ Dc,
    u16* __restrict__ ST) {
  int bh  = blockIdx.x >> 4;
  int e   = (blockIdx.x & 15) * 256 + threadIdx.x;  // 0..4095
  int i   = e >> 6;
  float acc = 0.f;
  for (int c = 0; c < 32; ++c) {
    float d  = Dc[(bh * 32 + c) * 64 + i];
    float uv = U[(size_t)(bh * 32 + c) * 4096 + e];
    ST[(size_t)(bh * 32 + c) * 4096 + e] = f2bf(acc);  // S_c (chunk-initial)
    acc = fmaf(d, acc, uv);                            // S_{c+1} = D*S + U
  }
}

// ---------------- K4: O = o_intra + RD@S_c (MFMA) + group-LN + gate --------
__global__ __launch_bounds__(128) void inter_ln(
    const u16* __restrict__ o, const u16* __restrict__ rd,
    const u16* __restrict__ rb, const u16* __restrict__ ST,
    const float* __restrict__ lnw, const float* __restrict__ lnb,
    u16* __restrict__ oh) {
  int c = blockIdx.x, bh = blockIdx.y;
  int b = bh >> 4, h = bh & 15;
  int tid = threadIdx.x, wave = tid >> 6, lane = tid & 63;
  int l15 = lane & 15, quad = lane >> 4;

  __shared__ __align__(16) u16 Sb[64][72];   // Sb[j][i] = S_c[i][j] (bf16)

  const u16* Sg = ST + (size_t)(bh * 32 + c) * 4096;
#pragma unroll
  for (int q = 0; q < 32; ++q) {
    int e = q * 128 + tid;
    Sb[e & 63][e >> 6] = Sg[e];
  }
  __syncthreads();

  size_t rbase = ((size_t)(b * 1024 + c * 32)) * 1024 + h * 64;

  const u16* rdg = rd + rbase + (size_t)(wave * 16 + l15) * 1024 + quad * 8;
  bf16x8 af0 = *(const bf16x8*)(rdg);
  bf16x8 af1 = *(const bf16x8*)(rdg + 32);

  f32x4 acc[4] = {};
#pragma unroll
  for (int nt = 0; nt < 4; ++nt) {
    const u16* bp = &Sb[nt * 16 + l15][quad * 8];
    bf16x8 b0 = *(const bf16x8*)bp;
    bf16x8 b1 = *(const bf16x8*)(bp + 32);
    acc[nt] = __builtin_amdgcn_mfma_f32_16x16x32_bf16(af0, b0, acc[nt], 0, 0, 0);
    acc[nt] = __builtin_amdgcn_mfma_f32_16x16x32_bf16(af1, b1, acc[nt], 0, 0, 0);
  }

#pragma unroll
  for (int rg = 0; rg < 4; ++rg) {
    int t = wave * 16 + quad * 4 + rg;
    size_t rowb = rbase + (size_t)t * 1024;
    float v[4];
    float s1 = 0.f, s2 = 0.f;
#pragma unroll
    for (int nt = 0; nt < 4; ++nt) {
      v[nt] = acc[nt][rg] + bf2f(o[rowb + nt * 16 + l15]);
      s1 += v[nt];
      s2 += v[nt] * v[nt];
    }
#pragma unroll
    for (int m = 1; m < 16; m <<= 1) {   // reduce across the quad's 16 lanes
      s1 += __shfl_xor(s1, m, 64);
      s2 += __shfl_xor(s2, m, 64);
    }
    float mu  = s1 * (1.f / 64.f);
    float var = s2 * (1.f / 64.f) - mu * mu;
    float rstd = rsqrtf(var + 1e-5f);
#pragma unroll
    for (int nt = 0; nt < 4; ++nt) {
      int jj = nt * 16 + l15;
      float nv = (v[nt] - mu) * rstd;
      float val = (nv * lnw[jj] + lnb[jj]) * bf2f(rb[rowb + jj]);
      oh[rowb + jj] = f2bf(val);
    }
  }
}

// ---------------- launch -----------------------------------------------------
extern "C" void kernel_launch(void* const* d_in, const int* in_sizes, int n_in,
                              void* d_out, int out_size, void* d_ws, size_t ws_size,
                              hipStream_t stream) {
  const float* x    = (const float*)d_in[0];
  const float* W_r  = (const float*)d_in[1];
  const float* W_k  = (const float*)d_in[2];
  const float* W_v  = (const float*)d_in[3];
  const float* W_w  = (const float*)d_in[4];
  const float* W_o  = (const float*)d_in[5];
  const float* u    = (const float*)d_in[6];
  const float* tm_r = (const float*)d_in[7];
  const float* tm_k = (const float*)d_in[8];
  const float* tm_v = (const float*)d_in[9];
  const float* tm_w = (const float*)d_in[10];
  const float* ln_w = (const float*)d_in[11];
  const float* ln_b = (const float*)d_in[12];
  float* out = (float*)d_out;

  char* ws = (char*)d_ws;
  // region [0,32)MB: xr..xw during prep/gemm_proj; reused as Ubuf afterwards
  u16* xr = (u16*)(ws + (size_t)0 * MB);
  u16* xk = (u16*)(ws + (size_t)8 * MB);
  u16* xv = (u16*)(ws + (size_t)16 * MB);
  u16* xw = (u16*)(ws + (size_t)24 * MB);
  float* Ubuf = (float*)(ws + (size_t)0 * MB);   // 32MB (64bh x 32c x 4096)
  u16* Wb = (u16*)(ws + (size_t)32 * MB);   // 5 x 2MB: Wr,Wk,Wv,Ww,Wo
  u16* Wrb = Wb;
  u16* Wkb = (u16*)(ws + (size_t)34 * MB);
  u16* Wvb = (u16*)(ws + (size_t)36 * MB);
  u16* Wwb = (u16*)(ws + (size_t)38 * MB);
  u16* Wob = (u16*)(ws + (size_t)40 * MB);
  float* Dcbuf = (float*)(ws + (size_t)42 * MB); // 512KB (64bh x 32c x 64)
  u16*   rbuf = (u16*)(ws + (size_t)48 * MB);    // 8MB bf16
  u16*   kbuf = (u16*)(ws + (size_t)56 * MB);    // 8MB bf16
  u16*   vbuf = (u16*)(ws + (size_t)64 * MB);    // 8MB bf16
  float* wbuf = (float*)(ws + (size_t)72 * MB);  // 16MB fp32 (raw z for decay)
  u16*   Sbuf = (u16*)(ws + (size_t)72 * MB);    // 16MB bf16 S_c — reuses wbuf
                                                 // (wbuf dead after scan_intra)
  u16*   obuf = (u16*)(ws + (size_t)88 * MB);    // 8MB bf16 o_intra
  u16*  rdbuf = (u16*)(ws + (size_t)104 * MB);   // 8MB bf16
  u16*   ohbuf = (u16*)(ws + (size_t)129 * MB);  // 8MB

  prep_all<<<18432, 256, 0, stream>>>(W_r, W_k, W_v, W_w, W_o, (u32*)Wb,
                                      x, tm_r, tm_k, tm_v, tm_w,
                                      (u32*)xr, (u32*)xk, (u32*)xv, (u32*)xw);
  gemm_proj<<<dim3(16, 4, 4), 512, 0, stream>>>(xr, xk, xv, xw,
                                                Wrb, Wkb, Wvb, Wwb,
                                                rbuf, kbuf, vbuf, wbuf);
  scan_intra<<<dim3(32, 64), 256, 0, stream>>>(rbuf, kbuf, vbuf, wbuf, u,
                                               obuf, rdbuf, Ubuf, Dcbuf);
  state_prop<<<1024, 256, 0, stream>>>(Ubuf, Dcbuf, Sbuf);
  inter_ln<<<dim3(32, 64), 128, 0, stream>>>(obuf, rdbuf, rbuf, Sbuf,
                                             ln_w, ln_b, ohbuf);
  gemm_out_sk<<<dim3(32, 8), 512, 0, stream>>>(ohbuf, Wob, out);
}